// Round 1
// baseline (712.941 us; speedup 1.0000x reference)
//
#include <hip/hip_runtime.h>
#include <math.h>

#define NN 100000
#define NE 1600000
#define CH 128
#define OUTC 16
#define NG 64

// ---------------- init: zero counters ----------------
__global__ void k_init(int* __restrict__ degi, int* __restrict__ fill,
                       float* __restrict__ pooled, float* __restrict__ cnt) {
    int i = blockIdx.x * 256 + threadIdx.x;
    if (i < NN) { degi[i] = 0; fill[i] = 0; }
    if (i < NG * CH) pooled[i] = 0.f;
    if (i < NG) cnt[i] = 0.f;
}

// ---------------- degree count (by dst) ----------------
__global__ void k_degcount(const int* __restrict__ dst, int* __restrict__ degi) {
    int e = blockIdx.x * 256 + threadIdx.x;
    if (e < NE) atomicAdd(&degi[dst[e]], 1);
}

// ---------------- dis = rsqrt(deg+1) ----------------
__global__ void k_dis(const int* __restrict__ degi, float* __restrict__ dis) {
    int i = blockIdx.x * 256 + threadIdx.x;
    if (i < NN) dis[i] = rsqrtf((float)degi[i] + 1.0f);
}

// ---------------- scan stage 1: per-block inclusive scan ----------------
__global__ void k_scan1(const int* __restrict__ degi, int* __restrict__ rowst,
                        int* __restrict__ partials) {
    __shared__ int s[1024];
    int t = threadIdx.x;
    int i = blockIdx.x * 1024 + t;
    int v = (i < NN) ? degi[i] : 0;
    s[t] = v;
    __syncthreads();
    for (int off = 1; off < 1024; off <<= 1) {
        int tmp = (t >= off) ? s[t - off] : 0;
        __syncthreads();
        s[t] += tmp;
        __syncthreads();
    }
    if (i < NN) rowst[i] = s[t];  // inclusive for now
    if (t == 1023) partials[blockIdx.x] = s[1023];
}

// ---------------- scan stage 2: exclusive scan of 98 partials ----------------
__global__ void k_scan2(int* __restrict__ partials, int nblocks) {
    if (threadIdx.x == 0) {
        int run = 0;
        for (int j = 0; j < nblocks; j++) { int t = partials[j]; partials[j] = run; run += t; }
    }
}

// ---------------- scan stage 3: make exclusive + add block offset ----------------
__global__ void k_scan3(const int* __restrict__ degi, const int* __restrict__ partials,
                        int* __restrict__ rowst) {
    int i = blockIdx.x * 256 + threadIdx.x;
    if (i < NN) rowst[i] = rowst[i] - degi[i] + partials[i >> 10];
}

// ---------------- CSR fill ----------------
__global__ void k_fill(const int* __restrict__ src, const int* __restrict__ dst,
                       const int* __restrict__ rowst, int* __restrict__ fill,
                       int* __restrict__ csr) {
    int e = blockIdx.x * 256 + threadIdx.x;
    if (e < NE) {
        int d = dst[e];
        int p = atomicAdd(&fill[d], 1);
        csr[rowst[d] + p] = src[e];
    }
}

// ---------------- GEMM: out[row] = (in[row] @ W) * dis[row] ----------------
// 32 rows/block, 256 threads, 4x4 register tile, K split in 2 passes (40KB LDS)
__launch_bounds__(256, 2)
__global__ void k_gemm_scale(const float* __restrict__ in, const float* __restrict__ W,
                             const float* __restrict__ dis, float* __restrict__ out) {
    __shared__ float ws[64][128];  // 32 KB: K-half x C
    __shared__ float xs[32][64];   // 8 KB: rows x K-half
    int tid = threadIdx.x;
    int b0 = blockIdx.x * 32;
    int cg = tid & 31;   // channel group -> channels cg*4..+3
    int rg = tid >> 5;   // row group -> rows rg*4..+3
    int c0 = cg * 4;

    float4 acc[4];
#pragma unroll
    for (int r = 0; r < 4; r++) acc[r] = make_float4(0.f, 0.f, 0.f, 0.f);

    for (int p = 0; p < 2; p++) {
        __syncthreads();
        // load W half: 64x128 = 2048 float4
#pragma unroll
        for (int i = 0; i < 8; i++) {
            int lin = tid + i * 256;           // 0..2047
            int r = lin >> 5, c4 = (lin & 31) * 4;
            *(float4*)&ws[r][c4] = *(const float4*)&W[(size_t)(p * 64 + r) * 128 + c4];
        }
        // load x tile half: 32x64 = 512 float4
#pragma unroll
        for (int i = 0; i < 2; i++) {
            int lin = tid + i * 256;           // 0..511
            int r = lin >> 4, c4 = (lin & 15) * 4;
            *(float4*)&xs[r][c4] = *(const float4*)&in[(size_t)(b0 + r) * 128 + p * 64 + c4];
        }
        __syncthreads();

        for (int k0 = 0; k0 < 64; k0 += 4) {
            float4 wv0 = *(float4*)&ws[k0 + 0][c0];
            float4 wv1 = *(float4*)&ws[k0 + 1][c0];
            float4 wv2 = *(float4*)&ws[k0 + 2][c0];
            float4 wv3 = *(float4*)&ws[k0 + 3][c0];
#pragma unroll
            for (int r = 0; r < 4; r++) {
                float4 xv = *(float4*)&xs[rg * 4 + r][k0];
                acc[r].x = fmaf(xv.x, wv0.x, acc[r].x);
                acc[r].y = fmaf(xv.x, wv0.y, acc[r].y);
                acc[r].z = fmaf(xv.x, wv0.z, acc[r].z);
                acc[r].w = fmaf(xv.x, wv0.w, acc[r].w);
                acc[r].x = fmaf(xv.y, wv1.x, acc[r].x);
                acc[r].y = fmaf(xv.y, wv1.y, acc[r].y);
                acc[r].z = fmaf(xv.y, wv1.z, acc[r].z);
                acc[r].w = fmaf(xv.y, wv1.w, acc[r].w);
                acc[r].x = fmaf(xv.z, wv2.x, acc[r].x);
                acc[r].y = fmaf(xv.z, wv2.y, acc[r].y);
                acc[r].z = fmaf(xv.z, wv2.z, acc[r].z);
                acc[r].w = fmaf(xv.z, wv2.w, acc[r].w);
                acc[r].x = fmaf(xv.w, wv3.x, acc[r].x);
                acc[r].y = fmaf(xv.w, wv3.y, acc[r].y);
                acc[r].z = fmaf(xv.w, wv3.z, acc[r].z);
                acc[r].w = fmaf(xv.w, wv3.w, acc[r].w);
            }
        }
    }
#pragma unroll
    for (int r = 0; r < 4; r++) {
        int row = b0 + rg * 4 + r;
        float d = dis[row];
        float4 v = make_float4(acc[r].x * d, acc[r].y * d, acc[r].z * d, acc[r].w * d);
        *(float4*)&out[(size_t)row * 128 + c0] = v;
    }
}

// ---------------- aggregation: out = relu(dis*(gather+self) + b) ----------------
// one wave per node, float2 per lane (128 ch / 64 lanes)
__global__ void k_agg(const float* __restrict__ ht, const int* __restrict__ rowst,
                      const int* __restrict__ degi, const int* __restrict__ csr,
                      const float* __restrict__ dis, const float* __restrict__ bias,
                      float* __restrict__ out) {
    int wave = threadIdx.x >> 6;
    int lane = threadIdx.x & 63;
    int n = blockIdx.x * 4 + wave;
    if (n >= NN) return;
    const float2* base = (const float2*)ht;
    float2 self = base[(size_t)n * 64 + lane];
    float ax = self.x, ay = self.y, bx = 0.f, by = 0.f;
    int start = rowst[n], c = degi[n];
    int j = 0;
    for (; j + 1 < c; j += 2) {
        int s0 = csr[start + j];
        int s1 = csr[start + j + 1];
        float2 v0 = base[(size_t)s0 * 64 + lane];
        float2 v1 = base[(size_t)s1 * 64 + lane];
        ax += v0.x; ay += v0.y;
        bx += v1.x; by += v1.y;
    }
    if (j < c) {
        int s0 = csr[start + j];
        float2 v0 = base[(size_t)s0 * 64 + lane];
        ax += v0.x; ay += v0.y;
    }
    float d = dis[n];
    float2 bb = *(const float2*)&bias[lane * 2];
    float ox = fmaxf(fmaf(d, ax + bx, bb.x), 0.f);
    float oy = fmaxf(fmaf(d, ay + by, bb.y), 0.f);
    ((float2*)out)[(size_t)n * 64 + lane] = make_float2(ox, oy);
}

// ---------------- mean pool partials (batch is sorted) ----------------
__global__ void k_pool(const float* __restrict__ h, const int* __restrict__ batch,
                       float* __restrict__ pooled, float* __restrict__ cnt) {
    int t = threadIdx.x;  // channel 0..127
    int n0 = blockIdx.x * 256;
    int n1 = n0 + 256;
    if (n1 > NN) n1 = NN;
    if (n0 >= NN) return;
    int gcur = batch[n0];
    float sum = 0.f, c = 0.f;
    for (int n = n0; n < n1; n++) {
        int g = batch[n];
        if (g != gcur) {
            atomicAdd(&pooled[gcur * CH + t], sum);
            if (t == 0) atomicAdd(&cnt[gcur], c);
            sum = 0.f; c = 0.f; gcur = g;
        }
        sum += h[(size_t)n * CH + t];
        c += 1.f;
    }
    atomicAdd(&pooled[gcur * CH + t], sum);
    if (t == 0) atomicAdd(&cnt[gcur], c);
}

// ---------------- final FC: out = (pooled/cnt) @ Wfc + bfc ----------------
__global__ void k_final(const float* __restrict__ pooled, const float* __restrict__ cnt,
                        const float* __restrict__ Wfc, const float* __restrict__ bfc,
                        float* __restrict__ out) {
    int idx = blockIdx.x * 256 + threadIdx.x;
    if (idx >= NG * OUTC) return;
    int g = idx >> 4, o = idx & 15;
    float inv = 1.0f / fmaxf(cnt[g], 1.0f);
    float s = 0.f;
    for (int k = 0; k < CH; k++) s += pooled[g * CH + k] * Wfc[k * OUTC + o];
    out[idx] = fmaf(s, inv, bfc[o]);
}

extern "C" void kernel_launch(void* const* d_in, const int* in_sizes, int n_in,
                              void* d_out, int out_size, void* d_ws, size_t ws_size,
                              hipStream_t stream) {
    (void)in_sizes; (void)n_in; (void)out_size; (void)ws_size;
    const float* x   = (const float*)d_in[0];
    const float* W1  = (const float*)d_in[1];
    const float* b1  = (const float*)d_in[2];
    const float* W2  = (const float*)d_in[3];
    const float* b2  = (const float*)d_in[4];
    const float* Wfc = (const float*)d_in[5];
    const float* bfc = (const float*)d_in[6];
    const int* ei    = (const int*)d_in[7];   // [2, NE]
    const int* batch = (const int*)d_in[8];
    const int* esrc = ei;
    const int* edst = ei + NE;
    float* out = (float*)d_out;

    // workspace carve-up
    char* w = (char*)d_ws;
    float* bufA = (float*)w;  w += (size_t)NN * CH * 4;   // 51.2 MB
    float* bufB = (float*)w;  w += (size_t)NN * CH * 4;   // 51.2 MB
    int* csr    = (int*)w;    w += (size_t)NE * 4;        // 6.4 MB
    int* degi   = (int*)w;    w += (size_t)NN * 4;
    int* rowst  = (int*)w;    w += (size_t)NN * 4;
    int* fill   = (int*)w;    w += (size_t)NN * 4;
    float* dis  = (float*)w;  w += (size_t)NN * 4;
    float* pooled = (float*)w; w += (size_t)NG * CH * 4;
    float* cnt  = (float*)w;  w += (size_t)NG * 4;
    int* partials = (int*)w;  w += 128 * 4;

    const int nScan = (NN + 1023) / 1024;  // 98

    k_init<<<(NN + 255) / 256, 256, 0, stream>>>(degi, fill, pooled, cnt);
    k_degcount<<<(NE + 255) / 256, 256, 0, stream>>>(edst, degi);
    k_dis<<<(NN + 255) / 256, 256, 0, stream>>>(degi, dis);
    k_scan1<<<nScan, 1024, 0, stream>>>(degi, rowst, partials);
    k_scan2<<<1, 64, 0, stream>>>(partials, nScan);
    k_scan3<<<(NN + 255) / 256, 256, 0, stream>>>(degi, partials, rowst);
    k_fill<<<(NE + 255) / 256, 256, 0, stream>>>(esrc, edst, rowst, fill, csr);

    // layer 1: bufA = (x@W1)*dis ; bufB = relu(dis*(gather(bufA)+bufA) + b1)
    k_gemm_scale<<<NN / 32, 256, 0, stream>>>(x, W1, dis, bufA);
    k_agg<<<NN / 4, 256, 0, stream>>>(bufA, rowst, degi, csr, dis, b1, bufB);
    // layer 2
    k_gemm_scale<<<NN / 32, 256, 0, stream>>>(bufB, W2, dis, bufA);
    k_agg<<<NN / 4, 256, 0, stream>>>(bufA, rowst, degi, csr, dis, b2, bufB);

    // pool + FC
    k_pool<<<(NN + 255) / 256, 128, 0, stream>>>(bufB, batch, pooled, cnt);
    k_final<<<(NG * OUTC + 255) / 256, 256, 0, stream>>>(pooled, cnt, Wfc, bfc, out);
}

// Round 2
// 568.168 us; speedup vs baseline: 1.2548x; 1.2548x over previous
//
#include <hip/hip_runtime.h>
#include <math.h>

#define NN 100000
#define NE 1600000
#define CH 128
#define OUTC 16
#define NG 64

typedef __attribute__((ext_vector_type(8))) short bf16x8;
typedef __attribute__((ext_vector_type(4))) float f32x4;

__device__ __forceinline__ unsigned short f2bf(float f) {
    union { float f; unsigned u; } v; v.f = f;
    unsigned r = v.u + 0x7FFF + ((v.u >> 16) & 1);   // RNE
    return (unsigned short)(r >> 16);
}
__device__ __forceinline__ float bflo(unsigned u) {  // low bf16 of packed pair
    union { unsigned u; float f; } v; v.u = u << 16; return v.f;
}
__device__ __forceinline__ float bfhi(unsigned u) {  // high bf16 of packed pair
    union { unsigned u; float f; } v; v.u = u & 0xffff0000u; return v.f;
}

// ---------------- init: zero counters ----------------
__global__ void k_init(int* __restrict__ degi, int* __restrict__ fill,
                       float* __restrict__ pooled, float* __restrict__ cnt) {
    int i = blockIdx.x * 256 + threadIdx.x;
    if (i < NN) { degi[i] = 0; fill[i] = 0; }
    if (i < NG * CH) pooled[i] = 0.f;
    if (i < NG) cnt[i] = 0.f;
}

// ---------------- degree count (by dst) ----------------
__global__ void k_degcount(const int* __restrict__ dst, int* __restrict__ degi) {
    int e = blockIdx.x * 256 + threadIdx.x;
    if (e < NE) atomicAdd(&degi[dst[e]], 1);
}

// ---------------- dis = rsqrt(deg+1) ----------------
__global__ void k_dis(const int* __restrict__ degi, float* __restrict__ dis) {
    int i = blockIdx.x * 256 + threadIdx.x;
    if (i < NN) dis[i] = rsqrtf((float)degi[i] + 1.0f);
}

// ---------------- scan stage 1: per-block inclusive scan ----------------
__global__ void k_scan1(const int* __restrict__ degi, int* __restrict__ rowst,
                        int* __restrict__ partials) {
    __shared__ int s[1024];
    int t = threadIdx.x;
    int i = blockIdx.x * 1024 + t;
    int v = (i < NN) ? degi[i] : 0;
    s[t] = v;
    __syncthreads();
    for (int off = 1; off < 1024; off <<= 1) {
        int tmp = (t >= off) ? s[t - off] : 0;
        __syncthreads();
        s[t] += tmp;
        __syncthreads();
    }
    if (i < NN) rowst[i] = s[t];  // inclusive for now
    if (t == 1023) partials[blockIdx.x] = s[1023];
}

// ---------------- scan stage 2: exclusive scan of partials ----------------
__global__ void k_scan2(int* __restrict__ partials, int nblocks) {
    if (threadIdx.x == 0) {
        int run = 0;
        for (int j = 0; j < nblocks; j++) { int t = partials[j]; partials[j] = run; run += t; }
    }
}

// ---------------- scan stage 3: make exclusive + add block offset ----------------
__global__ void k_scan3(const int* __restrict__ degi, const int* __restrict__ partials,
                        int* __restrict__ rowst) {
    int i = blockIdx.x * 256 + threadIdx.x;
    if (i < NN) rowst[i] = rowst[i] - degi[i] + partials[i >> 10];
}

// ---------------- CSR fill ----------------
__global__ void k_fill(const int* __restrict__ src, const int* __restrict__ dst,
                       const int* __restrict__ rowst, int* __restrict__ fill,
                       int* __restrict__ csr) {
    int e = blockIdx.x * 256 + threadIdx.x;
    if (e < NE) {
        int d = dst[e];
        int p = atomicAdd(&fill[d], 1);
        csr[rowst[d] + p] = src[e];
    }
}

// ---------------- fp32 -> bf16 cast (x) ----------------
__global__ void k_cast(const float* __restrict__ in, unsigned short* __restrict__ out, int n4) {
    int i = blockIdx.x * 256 + threadIdx.x;   // one float4 per thread
    if (i >= n4) return;
    float4 v = *(const float4*)&in[(size_t)i * 4];
    ushort4 o;
    o.x = f2bf(v.x); o.y = f2bf(v.y); o.z = f2bf(v.z); o.w = f2bf(v.w);
    *(ushort4*)&out[(size_t)i * 4] = o;
}

// ---------------- W [K][N] fp32 -> WT [N][K] bf16 ----------------
__global__ void k_castW(const float* __restrict__ W, unsigned short* __restrict__ WT) {
    int i = blockIdx.x * 256 + threadIdx.x;   // 16384
    if (i >= CH * CH) return;
    int k = i >> 7, n = i & 127;
    WT[n * CH + k] = f2bf(W[k * CH + n]);
}

// ---------------- MFMA GEMM: out[row] = bf16( (A[row] @ W) * dis[row] ) ----------------
// A bf16 [NN][128] row-major, WT bf16 [128][128] = W^T (so WT[n][k]).
// Block 256 = 4 waves; each wave: 16 rows x 128 cols (8 tiles of 16x16, K=128 in 4 steps).
__launch_bounds__(256, 2)
__global__ void k_gemm_mfma(const unsigned short* __restrict__ A,
                            const unsigned short* __restrict__ WT,
                            const float* __restrict__ dis,
                            unsigned short* __restrict__ out) {
    int tid = threadIdx.x;
    int wave = tid >> 6, lane = tid & 63;
    int quad = lane >> 4, l16 = lane & 15;

    int row = blockIdx.x * 64 + wave * 16 + l16;
    int rowc = row < NN ? row : NN - 1;

    // A fragments: 4 K-steps, each 8 contiguous bf16 at k = ks*32 + quad*8
    const unsigned short* arow = A + (size_t)rowc * CH + quad * 8;
    bf16x8 af0 = *(const bf16x8*)(arow);
    bf16x8 af1 = *(const bf16x8*)(arow + 32);
    bf16x8 af2 = *(const bf16x8*)(arow + 64);
    bf16x8 af3 = *(const bf16x8*)(arow + 96);

    f32x4 acc[8];
#pragma unroll
    for (int t = 0; t < 8; t++) acc[t] = (f32x4){0.f, 0.f, 0.f, 0.f};

#pragma unroll
    for (int t = 0; t < 8; t++) {
        const unsigned short* wcol = WT + (size_t)(t * 16 + l16) * CH + quad * 8;
        bf16x8 b0 = *(const bf16x8*)(wcol);
        bf16x8 b1 = *(const bf16x8*)(wcol + 32);
        bf16x8 b2 = *(const bf16x8*)(wcol + 64);
        bf16x8 b3 = *(const bf16x8*)(wcol + 96);
        acc[t] = __builtin_amdgcn_mfma_f32_16x16x32_bf16(af0, b0, acc[t], 0, 0, 0);
        acc[t] = __builtin_amdgcn_mfma_f32_16x16x32_bf16(af1, b1, acc[t], 0, 0, 0);
        acc[t] = __builtin_amdgcn_mfma_f32_16x16x32_bf16(af2, b2, acc[t], 0, 0, 0);
        acc[t] = __builtin_amdgcn_mfma_f32_16x16x32_bf16(af3, b3, acc[t], 0, 0, 0);
    }

    // D layout: row = quad*4 + r, col = l16  (per 16x16 tile)
    int rbase = blockIdx.x * 64 + wave * 16 + quad * 4;
#pragma unroll
    for (int r = 0; r < 4; r++) {
        int orow = rbase + r;
        if (orow < NN) {
            float d = dis[orow];
#pragma unroll
            for (int t = 0; t < 8; t++) {
                out[(size_t)orow * CH + t * 16 + l16] = f2bf(acc[t][r] * d);
            }
        }
    }
}

// ---------------- aggregation: out = bf16(relu(dis*(gather+self) + b)) ----------------
// one wave per node, one packed bf16x2 (4B) per lane
__global__ void k_agg(const unsigned short* __restrict__ ht, const int* __restrict__ rowst,
                      const int* __restrict__ degi, const int* __restrict__ csr,
                      const float* __restrict__ dis, const float* __restrict__ bias,
                      unsigned short* __restrict__ out) {
    int wave = threadIdx.x >> 6;
    int lane = threadIdx.x & 63;
    int n = blockIdx.x * 4 + wave;
    if (n >= NN) return;
    const unsigned* base = (const unsigned*)ht;   // [NN][64] packed pairs
    unsigned sv = base[(size_t)n * 64 + lane];
    float a0 = bflo(sv), a1 = bfhi(sv);
    float b0 = 0.f, b1 = 0.f, c0 = 0.f, c1 = 0.f, d0 = 0.f, d1 = 0.f;
    int start = rowst[n], c = degi[n];
    int j = 0;
    for (; j + 3 < c; j += 4) {
        int s0 = csr[start + j];
        int s1 = csr[start + j + 1];
        int s2 = csr[start + j + 2];
        int s3 = csr[start + j + 3];
        unsigned v0 = base[(size_t)s0 * 64 + lane];
        unsigned v1 = base[(size_t)s1 * 64 + lane];
        unsigned v2 = base[(size_t)s2 * 64 + lane];
        unsigned v3 = base[(size_t)s3 * 64 + lane];
        a0 += bflo(v0); a1 += bfhi(v0);
        b0 += bflo(v1); b1 += bfhi(v1);
        c0 += bflo(v2); c1 += bfhi(v2);
        d0 += bflo(v3); d1 += bfhi(v3);
    }
    for (; j < c; j++) {
        unsigned v0 = base[(size_t)csr[start + j] * 64 + lane];
        a0 += bflo(v0); a1 += bfhi(v0);
    }
    float sx = (a0 + b0) + (c0 + d0);
    float sy = (a1 + b1) + (c1 + d1);
    float d = dis[n];
    float bb0 = bias[lane * 2], bb1 = bias[lane * 2 + 1];
    float ox = fmaxf(fmaf(d, sx, bb0), 0.f);
    float oy = fmaxf(fmaf(d, sy, bb1), 0.f);
    unsigned pk = ((unsigned)f2bf(oy) << 16) | (unsigned)f2bf(ox);
    ((unsigned*)out)[(size_t)n * 64 + lane] = pk;
}

// ---------------- mean pool partials (batch sorted), bf16 input ----------------
__global__ void k_pool(const unsigned short* __restrict__ h, const int* __restrict__ batch,
                       float* __restrict__ pooled, float* __restrict__ cnt) {
    int t = threadIdx.x;  // channel 0..127
    int n0 = blockIdx.x * 256;
    int n1 = n0 + 256;
    if (n1 > NN) n1 = NN;
    if (n0 >= NN) return;
    int gcur = batch[n0];
    float sum = 0.f, c = 0.f;
    for (int n = n0; n < n1; n++) {
        int g = batch[n];
        if (g != gcur) {
            atomicAdd(&pooled[gcur * CH + t], sum);
            if (t == 0) atomicAdd(&cnt[gcur], c);
            sum = 0.f; c = 0.f; gcur = g;
        }
        union { unsigned u; float f; } v; v.u = ((unsigned)h[(size_t)n * CH + t]) << 16;
        sum += v.f;
        c += 1.f;
    }
    atomicAdd(&pooled[gcur * CH + t], sum);
    if (t == 0) atomicAdd(&cnt[gcur], c);
}

// ---------------- final FC: out = (pooled/cnt) @ Wfc + bfc ----------------
__global__ void k_final(const float* __restrict__ pooled, const float* __restrict__ cnt,
                        const float* __restrict__ Wfc, const float* __restrict__ bfc,
                        float* __restrict__ out) {
    int idx = blockIdx.x * 256 + threadIdx.x;
    if (idx >= NG * OUTC) return;
    int g = idx >> 4, o = idx & 15;
    float inv = 1.0f / fmaxf(cnt[g], 1.0f);
    float s = 0.f;
    for (int k = 0; k < CH; k++) s += pooled[g * CH + k] * Wfc[k * OUTC + o];
    out[idx] = fmaf(s, inv, bfc[o]);
}

extern "C" void kernel_launch(void* const* d_in, const int* in_sizes, int n_in,
                              void* d_out, int out_size, void* d_ws, size_t ws_size,
                              hipStream_t stream) {
    (void)in_sizes; (void)n_in; (void)out_size; (void)ws_size;
    const float* x   = (const float*)d_in[0];
    const float* W1  = (const float*)d_in[1];
    const float* b1  = (const float*)d_in[2];
    const float* W2  = (const float*)d_in[3];
    const float* b2  = (const float*)d_in[4];
    const float* Wfc = (const float*)d_in[5];
    const float* bfc = (const float*)d_in[6];
    const int* ei    = (const int*)d_in[7];   // [2, NE]
    const int* batch = (const int*)d_in[8];
    const int* esrc = ei;
    const int* edst = ei + NE;
    float* out = (float*)d_out;

    // workspace carve-up
    char* w = (char*)d_ws;
    unsigned short* xb   = (unsigned short*)w; w += (size_t)NN * CH * 2;  // 25.6 MB
    unsigned short* bufA = (unsigned short*)w; w += (size_t)NN * CH * 2;  // 25.6 MB
    unsigned short* bufB = (unsigned short*)w; w += (size_t)NN * CH * 2;  // 25.6 MB
    unsigned short* wt1  = (unsigned short*)w; w += (size_t)CH * CH * 2;  // 32 KB
    unsigned short* wt2  = (unsigned short*)w; w += (size_t)CH * CH * 2;  // 32 KB
    int* csr    = (int*)w;    w += (size_t)NE * 4;        // 6.4 MB
    int* degi   = (int*)w;    w += (size_t)NN * 4;
    int* rowst  = (int*)w;    w += (size_t)NN * 4;
    int* fill   = (int*)w;    w += (size_t)NN * 4;
    float* dis  = (float*)w;  w += (size_t)NN * 4;
    float* pooled = (float*)w; w += (size_t)NG * CH * 4;
    float* cnt  = (float*)w;  w += (size_t)NG * 4;
    int* partials = (int*)w;  w += 128 * 4;

    const int nScan = (NN + 1023) / 1024;  // 98

    k_init<<<(NN + 255) / 256, 256, 0, stream>>>(degi, fill, pooled, cnt);
    k_degcount<<<(NE + 255) / 256, 256, 0, stream>>>(edst, degi);
    k_dis<<<(NN + 255) / 256, 256, 0, stream>>>(degi, dis);
    k_scan1<<<nScan, 1024, 0, stream>>>(degi, rowst, partials);
    k_scan2<<<1, 64, 0, stream>>>(partials, nScan);
    k_scan3<<<(NN + 255) / 256, 256, 0, stream>>>(degi, partials, rowst);
    k_fill<<<(NE + 255) / 256, 256, 0, stream>>>(esrc, edst, rowst, fill, csr);

    // casts
    k_cast<<<(NN * CH / 4 + 255) / 256, 256, 0, stream>>>(x, xb, NN * CH / 4);
    k_castW<<<(CH * CH + 255) / 256, 256, 0, stream>>>(W1, wt1);
    k_castW<<<(CH * CH + 255) / 256, 256, 0, stream>>>(W2, wt2);

    const int gemmBlocks = (NN + 63) / 64;  // 1563

    // layer 1
    k_gemm_mfma<<<gemmBlocks, 256, 0, stream>>>(xb, wt1, dis, bufA);
    k_agg<<<NN / 4, 256, 0, stream>>>(bufA, rowst, degi, csr, dis, b1, bufB);
    // layer 2
    k_gemm_mfma<<<gemmBlocks, 256, 0, stream>>>(bufB, wt2, dis, bufA);
    k_agg<<<NN / 4, 256, 0, stream>>>(bufA, rowst, degi, csr, dis, b2, bufB);

    // pool + FC
    k_pool<<<(NN + 255) / 256, 128, 0, stream>>>(bufB, batch, pooled, cnt);
    k_final<<<(NG * OUTC + 255) / 256, 256, 0, stream>>>(pooled, cnt, Wfc, bfc, out);
}

// Round 3
// 440.207 us; speedup vs baseline: 1.6196x; 1.2907x over previous
//
#include <hip/hip_runtime.h>
#include <math.h>

#define NN 100000
#define NE 1600000
#define CH 128
#define OUTC 16
#define NG 64

#define CBSH 9                      // 512 nodes per coarse bucket
#define NCB 196                     // ceil(NN / 512)
#define CHK 8192                    // edges per passA block
#define MAXB 12288                  // csr staging capacity per bucket (avg 8192)

typedef __attribute__((ext_vector_type(8))) short bf16x8;
typedef __attribute__((ext_vector_type(4))) float f32x4;

__device__ __forceinline__ unsigned short f2bf(float f) {
    union { float f; unsigned u; } v; v.f = f;
    unsigned r = v.u + 0x7FFF + ((v.u >> 16) & 1);   // RNE
    return (unsigned short)(r >> 16);
}
__device__ __forceinline__ float bflo(unsigned u) {
    union { unsigned u; float f; } v; v.u = u << 16; return v.f;
}
__device__ __forceinline__ float bfhi(unsigned u) {
    union { unsigned u; float f; } v; v.u = u & 0xffff0000u; return v.f;
}

// ---------------- zero coarse-bucket counters ----------------
__global__ void k_init0(int* __restrict__ bcnt) {
    int i = blockIdx.x * 256 + threadIdx.x;
    if (i < NCB) bcnt[i] = 0;
}

// ---------------- coarse histogram: 196 buckets of 512 nodes ----------------
__global__ __launch_bounds__(1024) void k_hist(const int* __restrict__ dst, int* __restrict__ bcnt) {
    __shared__ int h[NCB];
    int t = threadIdx.x;
    if (t < NCB) h[t] = 0;
    __syncthreads();
    int base = blockIdx.x * CHK;
#pragma unroll
    for (int i = 0; i < 8; i++) {
        int e = base + i * 1024 + t;
        if (e < NE) atomicAdd(&h[dst[e] >> CBSH], 1);
    }
    __syncthreads();
    if (t < NCB && h[t]) atomicAdd(&bcnt[t], h[t]);
}

// ---------------- scan bucket counts -> ebase; zero gfill/pooled/cnt ----------------
__global__ __launch_bounds__(1024) void k_bscan(const int* __restrict__ bcnt, int* __restrict__ ebase,
                        int* __restrict__ gfill, float* __restrict__ pooled,
                        float* __restrict__ cnt) {
    __shared__ int s[256];
    int t = threadIdx.x;
    if (t < 256) s[t] = (t < NCB) ? bcnt[t] : 0;
    __syncthreads();
    for (int off = 1; off < 256; off <<= 1) {
        int v = 0;
        if (t < 256 && t >= off) v = s[t - off];
        __syncthreads();
        if (t < 256) s[t] += v;
        __syncthreads();
    }
    if (t == 0) ebase[0] = 0;
    if (t < NCB) { ebase[t + 1] = s[t]; gfill[t] = 0; }
    for (int i = t; i < NG * CH; i += 1024) pooled[i] = 0.f;
    if (t < NG) cnt[t] = 0.f;
}

// ---------------- pass A: counting-sort edges into coarse buckets ----------------
// packed entry: (src << 9) | (dst & 511); bucket recoverable from position.
__global__ __launch_bounds__(1024) void k_passA(const int* __restrict__ src, const int* __restrict__ dst,
                        const int* __restrict__ ebase, int* __restrict__ gfill,
                        unsigned* __restrict__ ebuf) {
    __shared__ unsigned lbuf[CHK];
    __shared__ int hcnt[NCB];
    __shared__ int hbase[256];   // inclusive scan of hcnt
    __shared__ int goff[NCB];
    int t = threadIdx.x;
    if (t < NCB) hcnt[t] = 0;
    __syncthreads();
    int base = blockIdx.x * CHK;
    int cb[8], slot[8]; unsigned pk[8];
#pragma unroll
    for (int i = 0; i < 8; i++) {
        int e = base + i * 1024 + t;
        cb[i] = -1;
        if (e < NE) {
            int d = dst[e], s = src[e];
            cb[i] = d >> CBSH;
            pk[i] = ((unsigned)s << CBSH) | (unsigned)(d & 511);
            slot[i] = atomicAdd(&hcnt[cb[i]], 1);
        }
    }
    __syncthreads();
    if (t < 256) hbase[t] = (t < NCB) ? hcnt[t] : 0;
    __syncthreads();
    for (int off = 1; off < 256; off <<= 1) {
        int v = 0;
        if (t < 256 && t >= off) v = hbase[t - off];
        __syncthreads();
        if (t < 256) hbase[t] += v;
        __syncthreads();
    }
    // reserve global space per bucket; goff maps local pos -> global pos
    if (t < NCB) {
        int c = hcnt[t];
        int g = c ? atomicAdd(&gfill[t], c) : 0;
        goff[t] = ebase[t] + g - (hbase[t] - c);
    }
    __syncthreads();
#pragma unroll
    for (int i = 0; i < 8; i++) {
        if (cb[i] >= 0) lbuf[hbase[cb[i]] - hcnt[cb[i]] + slot[i]] = pk[i];
    }
    __syncthreads();
    int total = min(NE - base, CHK);
    for (int p = t; p < total; p += 1024) {
        unsigned v = lbuf[p];
        // smallest cb with hbase[cb] > p
        int lo = 0, hi = NCB - 1;
        while (lo < hi) { int mid = (lo + hi) >> 1; if (hbase[mid] > p) hi = mid; else lo = mid + 1; }
        ebuf[goff[lo] + p] = v;
    }
}

// ---------------- pass B: per-bucket node sort -> csr/degi/rowst/dis ----------------
__global__ __launch_bounds__(1024) void k_passB(const unsigned* __restrict__ ebuf, const int* __restrict__ ebase,
                        int* __restrict__ degi, int* __restrict__ rowst,
                        float* __restrict__ dis, int* __restrict__ csr) {
    __shared__ int cnt[512];
    __shared__ int nbase[512];   // inclusive scan
    __shared__ int fill[512];
    __shared__ int stage[MAXB];
    int t = threadIdx.x;
    int cb = blockIdx.x;
    int nb0 = cb << CBSH;
    int ncnt = min(512, NN - nb0);
    int e0 = ebase[cb], e1 = ebase[cb + 1];
    if (t < 512) { cnt[t] = 0; fill[t] = 0; }
    __syncthreads();
    for (int e = e0 + t; e < e1; e += 1024)
        atomicAdd(&cnt[ebuf[e] & 511], 1);
    __syncthreads();
    if (t < 512) nbase[t] = cnt[t];
    __syncthreads();
    for (int off = 1; off < 512; off <<= 1) {
        int v = 0;
        if (t < 512 && t >= off) v = nbase[t - off];
        __syncthreads();
        if (t < 512) nbase[t] += v;
        __syncthreads();
    }
    for (int e = e0 + t; e < e1; e += 1024) {
        unsigned v = ebuf[e];
        int local = v & 511;
        int s = atomicAdd(&fill[local], 1);
        stage[nbase[local] - cnt[local] + s] = (int)(v >> CBSH);
    }
    __syncthreads();
    int total = e1 - e0;
    for (int p = t; p < total; p += 1024) csr[e0 + p] = stage[p];
    if (t < ncnt) {
        int c = cnt[t];
        degi[nb0 + t] = c;
        rowst[nb0 + t] = e0 + nbase[t] - c;
        dis[nb0 + t] = rsqrtf((float)c + 1.0f);
    }
}

// ---------------- fp32 -> bf16 cast (x) ----------------
__global__ void k_cast(const float* __restrict__ in, unsigned short* __restrict__ out, int n4) {
    int i = blockIdx.x * 256 + threadIdx.x;
    if (i >= n4) return;
    float4 v = *(const float4*)&in[(size_t)i * 4];
    ushort4 o;
    o.x = f2bf(v.x); o.y = f2bf(v.y); o.z = f2bf(v.z); o.w = f2bf(v.w);
    *(ushort4*)&out[(size_t)i * 4] = o;
}

// ---------------- both W [K][N] fp32 -> WT [N][K] bf16 ----------------
__global__ void k_castW(const float* __restrict__ W1, const float* __restrict__ W2,
                        unsigned short* __restrict__ wt1, unsigned short* __restrict__ wt2) {
    int i = blockIdx.x * 256 + threadIdx.x;
    if (i < CH * CH) {
        int k = i >> 7, n = i & 127;
        wt1[n * CH + k] = f2bf(W1[i]);
    } else if (i < 2 * CH * CH) {
        int j = i - CH * CH;
        int k = j >> 7, n = j & 127;
        wt2[n * CH + k] = f2bf(W2[j]);
    }
}

// ---------------- MFMA GEMM: out[row] = bf16( (A[row] @ W) * dis[row] ) ----------------
__launch_bounds__(256, 2)
__global__ void k_gemm_mfma(const unsigned short* __restrict__ A,
                            const unsigned short* __restrict__ WT,
                            const float* __restrict__ dis,
                            unsigned short* __restrict__ out) {
    int tid = threadIdx.x;
    int wave = tid >> 6, lane = tid & 63;
    int quad = lane >> 4, l16 = lane & 15;

    int row = blockIdx.x * 64 + wave * 16 + l16;
    int rowc = row < NN ? row : NN - 1;

    const unsigned short* arow = A + (size_t)rowc * CH + quad * 8;
    bf16x8 af0 = *(const bf16x8*)(arow);
    bf16x8 af1 = *(const bf16x8*)(arow + 32);
    bf16x8 af2 = *(const bf16x8*)(arow + 64);
    bf16x8 af3 = *(const bf16x8*)(arow + 96);

    f32x4 acc[8];
#pragma unroll
    for (int t = 0; t < 8; t++) acc[t] = (f32x4){0.f, 0.f, 0.f, 0.f};

#pragma unroll
    for (int t = 0; t < 8; t++) {
        const unsigned short* wcol = WT + (size_t)(t * 16 + l16) * CH + quad * 8;
        bf16x8 b0 = *(const bf16x8*)(wcol);
        bf16x8 b1 = *(const bf16x8*)(wcol + 32);
        bf16x8 b2 = *(const bf16x8*)(wcol + 64);
        bf16x8 b3 = *(const bf16x8*)(wcol + 96);
        acc[t] = __builtin_amdgcn_mfma_f32_16x16x32_bf16(af0, b0, acc[t], 0, 0, 0);
        acc[t] = __builtin_amdgcn_mfma_f32_16x16x32_bf16(af1, b1, acc[t], 0, 0, 0);
        acc[t] = __builtin_amdgcn_mfma_f32_16x16x32_bf16(af2, b2, acc[t], 0, 0, 0);
        acc[t] = __builtin_amdgcn_mfma_f32_16x16x32_bf16(af3, b3, acc[t], 0, 0, 0);
    }

    int rbase = blockIdx.x * 64 + wave * 16 + quad * 4;
#pragma unroll
    for (int r = 0; r < 4; r++) {
        int orow = rbase + r;
        if (orow < NN) {
            float d = dis[orow];
#pragma unroll
            for (int t = 0; t < 8; t++) {
                out[(size_t)orow * CH + t * 16 + l16] = f2bf(acc[t][r] * d);
            }
        }
    }
}

// ---------------- aggregation: out = bf16(relu(dis*(gather+self) + b)) ----------------
__global__ void k_agg(const unsigned short* __restrict__ ht, const int* __restrict__ rowst,
                      const int* __restrict__ degi, const int* __restrict__ csr,
                      const float* __restrict__ dis, const float* __restrict__ bias,
                      unsigned short* __restrict__ out) {
    int wave = threadIdx.x >> 6;
    int lane = threadIdx.x & 63;
    int n = blockIdx.x * 4 + wave;
    if (n >= NN) return;
    const unsigned* base = (const unsigned*)ht;
    unsigned sv = base[(size_t)n * 64 + lane];
    float a0 = bflo(sv), a1 = bfhi(sv);
    float b0 = 0.f, b1 = 0.f, c0 = 0.f, c1 = 0.f, d0 = 0.f, d1 = 0.f;
    int start = rowst[n], c = degi[n];
    int j = 0;
    for (; j + 3 < c; j += 4) {
        int s0 = csr[start + j];
        int s1 = csr[start + j + 1];
        int s2 = csr[start + j + 2];
        int s3 = csr[start + j + 3];
        unsigned v0 = base[(size_t)s0 * 64 + lane];
        unsigned v1 = base[(size_t)s1 * 64 + lane];
        unsigned v2 = base[(size_t)s2 * 64 + lane];
        unsigned v3 = base[(size_t)s3 * 64 + lane];
        a0 += bflo(v0); a1 += bfhi(v0);
        b0 += bflo(v1); b1 += bfhi(v1);
        c0 += bflo(v2); c1 += bfhi(v2);
        d0 += bflo(v3); d1 += bfhi(v3);
    }
    for (; j < c; j++) {
        unsigned v0 = base[(size_t)csr[start + j] * 64 + lane];
        a0 += bflo(v0); a1 += bfhi(v0);
    }
    float sx = (a0 + b0) + (c0 + d0);
    float sy = (a1 + b1) + (c1 + d1);
    float d = dis[n];
    float bb0 = bias[lane * 2], bb1 = bias[lane * 2 + 1];
    float ox = fmaxf(fmaf(d, sx, bb0), 0.f);
    float oy = fmaxf(fmaf(d, sy, bb1), 0.f);
    unsigned pk = ((unsigned)f2bf(oy) << 16) | (unsigned)f2bf(ox);
    ((unsigned*)out)[(size_t)n * 64 + lane] = pk;
}

// ---------------- mean pool partials (batch sorted), bf16 input ----------------
__global__ void k_pool(const unsigned short* __restrict__ h, const int* __restrict__ batch,
                       float* __restrict__ pooled, float* __restrict__ cnt) {
    int t = threadIdx.x;
    int n0 = blockIdx.x * 256;
    int n1 = n0 + 256;
    if (n1 > NN) n1 = NN;
    if (n0 >= NN) return;
    int gcur = batch[n0];
    float sum = 0.f, c = 0.f;
    for (int n = n0; n < n1; n++) {
        int g = batch[n];
        if (g != gcur) {
            atomicAdd(&pooled[gcur * CH + t], sum);
            if (t == 0) atomicAdd(&cnt[gcur], c);
            sum = 0.f; c = 0.f; gcur = g;
        }
        union { unsigned u; float f; } v; v.u = ((unsigned)h[(size_t)n * CH + t]) << 16;
        sum += v.f;
        c += 1.f;
    }
    atomicAdd(&pooled[gcur * CH + t], sum);
    if (t == 0) atomicAdd(&cnt[gcur], c);
}

// ---------------- final FC ----------------
__global__ void k_final(const float* __restrict__ pooled, const float* __restrict__ cnt,
                        const float* __restrict__ Wfc, const float* __restrict__ bfc,
                        float* __restrict__ out) {
    int idx = blockIdx.x * 256 + threadIdx.x;
    if (idx >= NG * OUTC) return;
    int g = idx >> 4, o = idx & 15;
    float inv = 1.0f / fmaxf(cnt[g], 1.0f);
    float s = 0.f;
    for (int k = 0; k < CH; k++) s += pooled[g * CH + k] * Wfc[k * OUTC + o];
    out[idx] = fmaf(s, inv, bfc[o]);
}

extern "C" void kernel_launch(void* const* d_in, const int* in_sizes, int n_in,
                              void* d_out, int out_size, void* d_ws, size_t ws_size,
                              hipStream_t stream) {
    (void)in_sizes; (void)n_in; (void)out_size; (void)ws_size;
    const float* x   = (const float*)d_in[0];
    const float* W1  = (const float*)d_in[1];
    const float* b1  = (const float*)d_in[2];
    const float* W2  = (const float*)d_in[3];
    const float* b2  = (const float*)d_in[4];
    const float* Wfc = (const float*)d_in[5];
    const float* bfc = (const float*)d_in[6];
    const int* ei    = (const int*)d_in[7];
    const int* batch = (const int*)d_in[8];
    const int* esrc = ei;
    const int* edst = ei + NE;
    float* out = (float*)d_out;

    char* w = (char*)d_ws;
    unsigned short* xb   = (unsigned short*)w; w += (size_t)NN * CH * 2;
    unsigned short* bufA = (unsigned short*)w; w += (size_t)NN * CH * 2;
    unsigned short* bufB = (unsigned short*)w; w += (size_t)NN * CH * 2;
    unsigned short* wt1  = (unsigned short*)w; w += (size_t)CH * CH * 2;
    unsigned short* wt2  = (unsigned short*)w; w += (size_t)CH * CH * 2;
    unsigned* ebuf = (unsigned*)w; w += (size_t)NE * 4;
    int* csr    = (int*)w;    w += (size_t)NE * 4;
    int* degi   = (int*)w;    w += (size_t)NN * 4;
    int* rowst  = (int*)w;    w += (size_t)NN * 4;
    float* dis  = (float*)w;  w += (size_t)NN * 4;
    int* bcnt   = (int*)w;    w += NCB * 4;
    int* ebase  = (int*)w;    w += (NCB + 1) * 4;
    int* gfill  = (int*)w;    w += NCB * 4;
    float* pooled = (float*)w; w += (size_t)NG * CH * 4;
    float* cnt  = (float*)w;  w += (size_t)NG * 4;

    const int histBlocks = (NE + CHK - 1) / CHK;   // 196

    k_init0<<<1, 256, 0, stream>>>(bcnt);
    k_hist<<<histBlocks, 1024, 0, stream>>>(edst, bcnt);
    k_bscan<<<1, 1024, 0, stream>>>(bcnt, ebase, gfill, pooled, cnt);
    k_passA<<<histBlocks, 1024, 0, stream>>>(esrc, edst, ebase, gfill, ebuf);
    k_passB<<<NCB, 1024, 0, stream>>>(ebuf, ebase, degi, rowst, dis, csr);

    k_cast<<<(NN * CH / 4 + 255) / 256, 256, 0, stream>>>(x, xb, NN * CH / 4);
    k_castW<<<(2 * CH * CH + 255) / 256, 256, 0, stream>>>(W1, W2, wt1, wt2);

    const int gemmBlocks = (NN + 63) / 64;

    k_gemm_mfma<<<gemmBlocks, 256, 0, stream>>>(xb, wt1, dis, bufA);
    k_agg<<<NN / 4, 256, 0, stream>>>(bufA, rowst, degi, csr, dis, b1, bufB);
    k_gemm_mfma<<<gemmBlocks, 256, 0, stream>>>(bufB, wt2, dis, bufA);
    k_agg<<<NN / 4, 256, 0, stream>>>(bufA, rowst, degi, csr, dis, b2, bufB);

    k_pool<<<(NN + 255) / 256, 128, 0, stream>>>(bufB, batch, pooled, cnt);
    k_final<<<(NG * OUTC + 255) / 256, 256, 0, stream>>>(pooled, cnt, Wfc, bfc, out);
}

// Round 4
// 377.782 us; speedup vs baseline: 1.8872x; 1.1652x over previous
//
#include <hip/hip_runtime.h>
#include <math.h>

#define NN 100000
#define NE 1600000
#define CH 128
#define OUTC 16
#define NG 64

#define CBSH 9                      // 512 nodes per coarse bucket
#define NCB 196                     // ceil(NN / 512)
#define CHK 8192                    // edges per passA block
#define MAXB 12288                  // csr staging capacity per bucket (avg 8192)
#define PS 8                        // pool splits per graph

typedef __attribute__((ext_vector_type(8))) short bf16x8;
typedef __attribute__((ext_vector_type(4))) float f32x4;

__device__ __forceinline__ unsigned short f2bf(float f) {
    union { float f; unsigned u; } v; v.f = f;
    unsigned r = v.u + 0x7FFF + ((v.u >> 16) & 1);   // RNE
    return (unsigned short)(r >> 16);
}
__device__ __forceinline__ float bflo(unsigned u) {
    union { unsigned u; float f; } v; v.u = u << 16; return v.f;
}
__device__ __forceinline__ float bfhi(unsigned u) {
    union { unsigned u; float f; } v; v.u = u & 0xffff0000u; return v.f;
}

// ---------------- zero coarse-bucket counters ----------------
__global__ void k_init0(int* __restrict__ bcnt) {
    int i = blockIdx.x * 256 + threadIdx.x;
    if (i < NCB) bcnt[i] = 0;
}

// ---------------- coarse histogram: 196 buckets of 512 nodes ----------------
__global__ __launch_bounds__(1024) void k_hist(const int* __restrict__ dst, int* __restrict__ bcnt) {
    __shared__ int h[NCB];
    int t = threadIdx.x;
    if (t < NCB) h[t] = 0;
    __syncthreads();
    int base = blockIdx.x * CHK;
#pragma unroll
    for (int i = 0; i < 8; i++) {
        int e = base + i * 1024 + t;
        if (e < NE) atomicAdd(&h[dst[e] >> CBSH], 1);
    }
    __syncthreads();
    if (t < NCB && h[t]) atomicAdd(&bcnt[t], h[t]);
}

// ---------------- scan bucket counts -> ebase; zero gfill/pooled ----------------
__global__ __launch_bounds__(1024) void k_bscan(const int* __restrict__ bcnt, int* __restrict__ ebase,
                        int* __restrict__ gfill, float* __restrict__ pooled) {
    __shared__ int s[256];
    int t = threadIdx.x;
    if (t < 256) s[t] = (t < NCB) ? bcnt[t] : 0;
    __syncthreads();
    for (int off = 1; off < 256; off <<= 1) {
        int v = 0;
        if (t < 256 && t >= off) v = s[t - off];
        __syncthreads();
        if (t < 256) s[t] += v;
        __syncthreads();
    }
    if (t == 0) ebase[0] = 0;
    if (t < NCB) { ebase[t + 1] = s[t]; gfill[t] = 0; }
    for (int i = t; i < NG * CH; i += 1024) pooled[i] = 0.f;
}

// ---------------- pass A: counting-sort edges into coarse buckets ----------------
__global__ __launch_bounds__(1024) void k_passA(const int* __restrict__ src, const int* __restrict__ dst,
                        const int* __restrict__ ebase, int* __restrict__ gfill,
                        unsigned* __restrict__ ebuf) {
    __shared__ unsigned lbuf[CHK];
    __shared__ int hcnt[NCB];
    __shared__ int hbase[256];   // inclusive scan of hcnt
    __shared__ int goff[NCB];
    int t = threadIdx.x;
    if (t < NCB) hcnt[t] = 0;
    __syncthreads();
    int base = blockIdx.x * CHK;
    int cb[8], slot[8]; unsigned pk[8];
#pragma unroll
    for (int i = 0; i < 8; i++) {
        int e = base + i * 1024 + t;
        cb[i] = -1;
        if (e < NE) {
            int d = dst[e], s = src[e];
            cb[i] = d >> CBSH;
            pk[i] = ((unsigned)s << CBSH) | (unsigned)(d & 511);
            slot[i] = atomicAdd(&hcnt[cb[i]], 1);
        }
    }
    __syncthreads();
    if (t < 256) hbase[t] = (t < NCB) ? hcnt[t] : 0;
    __syncthreads();
    for (int off = 1; off < 256; off <<= 1) {
        int v = 0;
        if (t < 256 && t >= off) v = hbase[t - off];
        __syncthreads();
        if (t < 256) hbase[t] += v;
        __syncthreads();
    }
    if (t < NCB) {
        int c = hcnt[t];
        int g = c ? atomicAdd(&gfill[t], c) : 0;
        goff[t] = ebase[t] + g - (hbase[t] - c);
    }
    __syncthreads();
#pragma unroll
    for (int i = 0; i < 8; i++) {
        if (cb[i] >= 0) lbuf[hbase[cb[i]] - hcnt[cb[i]] + slot[i]] = pk[i];
    }
    __syncthreads();
    int total = min(NE - base, CHK);
    for (int p = t; p < total; p += 1024) {
        unsigned v = lbuf[p];
        int lo = 0, hi = NCB - 1;
        while (lo < hi) { int mid = (lo + hi) >> 1; if (hbase[mid] > p) hi = mid; else lo = mid + 1; }
        ebuf[goff[lo] + p] = v;
    }
}

// ---------------- pass B: per-bucket node sort -> csr/degi/rowst/dis ----------------
__global__ __launch_bounds__(1024) void k_passB(const unsigned* __restrict__ ebuf, const int* __restrict__ ebase,
                        int* __restrict__ degi, int* __restrict__ rowst,
                        float* __restrict__ dis, int* __restrict__ csr) {
    __shared__ int cnt[512];
    __shared__ int nbase[512];
    __shared__ int fill[512];
    __shared__ int stage[MAXB];
    int t = threadIdx.x;
    int cb = blockIdx.x;
    int nb0 = cb << CBSH;
    int ncnt = min(512, NN - nb0);
    int e0 = ebase[cb], e1 = ebase[cb + 1];
    if (t < 512) { cnt[t] = 0; fill[t] = 0; }
    __syncthreads();
    for (int e = e0 + t; e < e1; e += 1024)
        atomicAdd(&cnt[ebuf[e] & 511], 1);
    __syncthreads();
    if (t < 512) nbase[t] = cnt[t];
    __syncthreads();
    for (int off = 1; off < 512; off <<= 1) {
        int v = 0;
        if (t < 512 && t >= off) v = nbase[t - off];
        __syncthreads();
        if (t < 512) nbase[t] += v;
        __syncthreads();
    }
    for (int e = e0 + t; e < e1; e += 1024) {
        unsigned v = ebuf[e];
        int local = v & 511;
        int s = atomicAdd(&fill[local], 1);
        stage[nbase[local] - cnt[local] + s] = (int)(v >> CBSH);
    }
    __syncthreads();
    int total = e1 - e0;
    for (int p = t; p < total; p += 1024) csr[e0 + p] = stage[p];
    if (t < ncnt) {
        int c = cnt[t];
        degi[nb0 + t] = c;
        rowst[nb0 + t] = e0 + nbase[t] - c;
        dis[nb0 + t] = rsqrtf((float)c + 1.0f);
    }
}

// ---------------- graph start offsets from sorted batch ----------------
__global__ void k_gptr(const int* __restrict__ batch, int* __restrict__ gptr) {
    int n = blockIdx.x * 256 + threadIdx.x;
    if (n >= NN) return;
    int b = batch[n];
    int prev = (n == 0) ? -1 : batch[n - 1];
    for (int g = prev + 1; g <= b; g++) gptr[g] = n;
    if (n == NN - 1) {
        for (int g = b + 1; g <= NG; g++) gptr[g] = NN;
    }
}

// ---------------- fp32 -> bf16 cast (x) ----------------
__global__ void k_cast(const float* __restrict__ in, unsigned short* __restrict__ out, int n4) {
    int i = blockIdx.x * 256 + threadIdx.x;
    if (i >= n4) return;
    float4 v = *(const float4*)&in[(size_t)i * 4];
    ushort4 o;
    o.x = f2bf(v.x); o.y = f2bf(v.y); o.z = f2bf(v.z); o.w = f2bf(v.w);
    *(ushort4*)&out[(size_t)i * 4] = o;
}

// ---------------- both W [K][N] fp32 -> WT [N][K] bf16 ----------------
__global__ void k_castW(const float* __restrict__ W1, const float* __restrict__ W2,
                        unsigned short* __restrict__ wt1, unsigned short* __restrict__ wt2) {
    int i = blockIdx.x * 256 + threadIdx.x;
    if (i < CH * CH) {
        int k = i >> 7, n = i & 127;
        wt1[n * CH + k] = f2bf(W1[i]);
    } else if (i < 2 * CH * CH) {
        int j = i - CH * CH;
        int k = j >> 7, n = j & 127;
        wt2[n * CH + k] = f2bf(W2[j]);
    }
}

// ---------------- MFMA GEMM: out[row] = bf16( (A[row] @ W) * dis[row] ) ----------------
__launch_bounds__(256, 2)
__global__ void k_gemm_mfma(const unsigned short* __restrict__ A,
                            const unsigned short* __restrict__ WT,
                            const float* __restrict__ dis,
                            unsigned short* __restrict__ out) {
    int tid = threadIdx.x;
    int wave = tid >> 6, lane = tid & 63;
    int quad = lane >> 4, l16 = lane & 15;

    int row = blockIdx.x * 64 + wave * 16 + l16;
    int rowc = row < NN ? row : NN - 1;

    const unsigned short* arow = A + (size_t)rowc * CH + quad * 8;
    bf16x8 af0 = *(const bf16x8*)(arow);
    bf16x8 af1 = *(const bf16x8*)(arow + 32);
    bf16x8 af2 = *(const bf16x8*)(arow + 64);
    bf16x8 af3 = *(const bf16x8*)(arow + 96);

    f32x4 acc[8];
#pragma unroll
    for (int t = 0; t < 8; t++) acc[t] = (f32x4){0.f, 0.f, 0.f, 0.f};

#pragma unroll
    for (int t = 0; t < 8; t++) {
        const unsigned short* wcol = WT + (size_t)(t * 16 + l16) * CH + quad * 8;
        bf16x8 b0 = *(const bf16x8*)(wcol);
        bf16x8 b1 = *(const bf16x8*)(wcol + 32);
        bf16x8 b2 = *(const bf16x8*)(wcol + 64);
        bf16x8 b3 = *(const bf16x8*)(wcol + 96);
        acc[t] = __builtin_amdgcn_mfma_f32_16x16x32_bf16(af0, b0, acc[t], 0, 0, 0);
        acc[t] = __builtin_amdgcn_mfma_f32_16x16x32_bf16(af1, b1, acc[t], 0, 0, 0);
        acc[t] = __builtin_amdgcn_mfma_f32_16x16x32_bf16(af2, b2, acc[t], 0, 0, 0);
        acc[t] = __builtin_amdgcn_mfma_f32_16x16x32_bf16(af3, b3, acc[t], 0, 0, 0);
    }

    int rbase = blockIdx.x * 64 + wave * 16 + quad * 4;
#pragma unroll
    for (int r = 0; r < 4; r++) {
        int orow = rbase + r;
        if (orow < NN) {
            float d = dis[orow];
#pragma unroll
            for (int t = 0; t < 8; t++) {
                out[(size_t)orow * CH + t * 16 + l16] = f2bf(acc[t][r] * d);
            }
        }
    }
}

// ---------------- aggregation: out = bf16(relu(dis*(gather+self) + b)) ----------------
__global__ void k_agg(const unsigned short* __restrict__ ht, const int* __restrict__ rowst,
                      const int* __restrict__ degi, const int* __restrict__ csr,
                      const float* __restrict__ dis, const float* __restrict__ bias,
                      unsigned short* __restrict__ out) {
    int wave = threadIdx.x >> 6;
    int lane = threadIdx.x & 63;
    int n = blockIdx.x * 4 + wave;
    if (n >= NN) return;
    const unsigned* base = (const unsigned*)ht;
    unsigned sv = base[(size_t)n * 64 + lane];
    float a0 = bflo(sv), a1 = bfhi(sv);
    float b0 = 0.f, b1 = 0.f, c0 = 0.f, c1 = 0.f, d0 = 0.f, d1 = 0.f;
    int start = rowst[n], c = degi[n];
    int j = 0;
    for (; j + 3 < c; j += 4) {
        int s0 = csr[start + j];
        int s1 = csr[start + j + 1];
        int s2 = csr[start + j + 2];
        int s3 = csr[start + j + 3];
        unsigned v0 = base[(size_t)s0 * 64 + lane];
        unsigned v1 = base[(size_t)s1 * 64 + lane];
        unsigned v2 = base[(size_t)s2 * 64 + lane];
        unsigned v3 = base[(size_t)s3 * 64 + lane];
        a0 += bflo(v0); a1 += bfhi(v0);
        b0 += bflo(v1); b1 += bfhi(v1);
        c0 += bflo(v2); c1 += bfhi(v2);
        d0 += bflo(v3); d1 += bfhi(v3);
    }
    for (; j < c; j++) {
        unsigned v0 = base[(size_t)csr[start + j] * 64 + lane];
        a0 += bflo(v0); a1 += bfhi(v0);
    }
    float sx = (a0 + b0) + (c0 + d0);
    float sy = (a1 + b1) + (c1 + d1);
    float d = dis[n];
    float bb0 = bias[lane * 2], bb1 = bias[lane * 2 + 1];
    float ox = fmaxf(fmaf(d, sx, bb0), 0.f);
    float oy = fmaxf(fmaf(d, sy, bb1), 0.f);
    unsigned pk = ((unsigned)f2bf(oy) << 16) | (unsigned)f2bf(ox);
    ((unsigned*)out)[(size_t)n * 64 + lane] = pk;
}

// ---------------- mean pool: 8 splits/graph, LDS reduce, few atomics ----------------
__global__ __launch_bounds__(512) void k_pool2(const unsigned short* __restrict__ h,
                                               const int* __restrict__ gptr,
                                               float* __restrict__ pooled) {
    int g = blockIdx.x >> 3;       // graph
    int s = blockIdx.x & 7;        // split
    int gs = gptr[g], ge = gptr[g + 1];
    int len = ge - gs;
    int i0 = gs + (int)(((long long)len * s) >> 3);
    int i1 = gs + (int)(((long long)len * (s + 1)) >> 3);
    int t = threadIdx.x;
    int pr = t & 63;               // channel pair 0..63
    int ro = t >> 6;               // row group 0..7
    const unsigned* base = (const unsigned*)h;
    float s0 = 0.f, s1 = 0.f;
    for (int n = i0 + ro; n < i1; n += 8) {
        unsigned v = base[(size_t)n * 64 + pr];
        s0 += bflo(v); s1 += bfhi(v);
    }
    __shared__ float red[2][8][64];
    red[0][ro][pr] = s0; red[1][ro][pr] = s1;
    __syncthreads();
    for (int off = 4; off >= 1; off >>= 1) {
        if (ro < off) {
            red[0][ro][pr] += red[0][ro + off][pr];
            red[1][ro][pr] += red[1][ro + off][pr];
        }
        __syncthreads();
    }
    if (ro == 0) {
        atomicAdd(&pooled[g * CH + pr * 2],     red[0][0][pr]);
        atomicAdd(&pooled[g * CH + pr * 2 + 1], red[1][0][pr]);
    }
}

// ---------------- final FC: out = (pooled/cnt) @ Wfc + bfc ----------------
__global__ void k_final(const float* __restrict__ pooled, const int* __restrict__ gptr,
                        const float* __restrict__ Wfc, const float* __restrict__ bfc,
                        float* __restrict__ out) {
    int idx = blockIdx.x * 256 + threadIdx.x;
    if (idx >= NG * OUTC) return;
    int g = idx >> 4, o = idx & 15;
    float c = (float)(gptr[g + 1] - gptr[g]);
    float inv = 1.0f / fmaxf(c, 1.0f);
    float s = 0.f;
    for (int k = 0; k < CH; k++) s += pooled[g * CH + k] * Wfc[k * OUTC + o];
    out[idx] = fmaf(s, inv, bfc[o]);
}

extern "C" void kernel_launch(void* const* d_in, const int* in_sizes, int n_in,
                              void* d_out, int out_size, void* d_ws, size_t ws_size,
                              hipStream_t stream) {
    (void)in_sizes; (void)n_in; (void)out_size; (void)ws_size;
    const float* x   = (const float*)d_in[0];
    const float* W1  = (const float*)d_in[1];
    const float* b1  = (const float*)d_in[2];
    const float* W2  = (const float*)d_in[3];
    const float* b2  = (const float*)d_in[4];
    const float* Wfc = (const float*)d_in[5];
    const float* bfc = (const float*)d_in[6];
    const int* ei    = (const int*)d_in[7];
    const int* batch = (const int*)d_in[8];
    const int* esrc = ei;
    const int* edst = ei + NE;
    float* out = (float*)d_out;

    char* w = (char*)d_ws;
    unsigned short* xb   = (unsigned short*)w; w += (size_t)NN * CH * 2;
    unsigned short* bufA = (unsigned short*)w; w += (size_t)NN * CH * 2;
    unsigned short* bufB = (unsigned short*)w; w += (size_t)NN * CH * 2;
    unsigned short* wt1  = (unsigned short*)w; w += (size_t)CH * CH * 2;
    unsigned short* wt2  = (unsigned short*)w; w += (size_t)CH * CH * 2;
    unsigned* ebuf = (unsigned*)w; w += (size_t)NE * 4;
    int* csr    = (int*)w;    w += (size_t)NE * 4;
    int* degi   = (int*)w;    w += (size_t)NN * 4;
    int* rowst  = (int*)w;    w += (size_t)NN * 4;
    float* dis  = (float*)w;  w += (size_t)NN * 4;
    int* bcnt   = (int*)w;    w += NCB * 4;
    int* ebase  = (int*)w;    w += (NCB + 1) * 4;
    int* gfill  = (int*)w;    w += NCB * 4;
    int* gptr   = (int*)w;    w += (NG + 1) * 4;
    float* pooled = (float*)w; w += (size_t)NG * CH * 4;

    const int histBlocks = (NE + CHK - 1) / CHK;   // 196

    k_init0<<<1, 256, 0, stream>>>(bcnt);
    k_hist<<<histBlocks, 1024, 0, stream>>>(edst, bcnt);
    k_bscan<<<1, 1024, 0, stream>>>(bcnt, ebase, gfill, pooled);
    k_passA<<<histBlocks, 1024, 0, stream>>>(esrc, edst, ebase, gfill, ebuf);
    k_passB<<<NCB, 1024, 0, stream>>>(ebuf, ebase, degi, rowst, dis, csr);
    k_gptr<<<(NN + 255) / 256, 256, 0, stream>>>(batch, gptr);

    k_cast<<<(NN * CH / 4 + 255) / 256, 256, 0, stream>>>(x, xb, NN * CH / 4);
    k_castW<<<(2 * CH * CH + 255) / 256, 256, 0, stream>>>(W1, W2, wt1, wt2);

    const int gemmBlocks = (NN + 63) / 64;

    k_gemm_mfma<<<gemmBlocks, 256, 0, stream>>>(xb, wt1, dis, bufA);
    k_agg<<<NN / 4, 256, 0, stream>>>(bufA, rowst, degi, csr, dis, b1, bufB);
    k_gemm_mfma<<<gemmBlocks, 256, 0, stream>>>(bufB, wt2, dis, bufA);
    k_agg<<<NN / 4, 256, 0, stream>>>(bufA, rowst, degi, csr, dis, b2, bufB);

    k_pool2<<<NG * PS, 512, 0, stream>>>(bufB, gptr, pooled);
    k_final<<<(NG * OUTC + 255) / 256, 256, 0, stream>>>(pooled, gptr, Wfc, bfc, out);
}

// Round 5
// 334.044 us; speedup vs baseline: 2.1343x; 1.1309x over previous
//
#include <hip/hip_runtime.h>
#include <math.h>

#define NN 100000
#define NE 1600000
#define CH 128
#define OUTC 16
#define NG 64

#define CBSH 9                      // 512 nodes per coarse bucket
#define NCB 196                     // ceil(NN / 512)
#define CHK 8192                    // edges per passA block
#define MAXB 12288                  // csr staging capacity per bucket (avg 8192)
#define PS 8                        // pool splits per graph

typedef __attribute__((ext_vector_type(8))) short bf16x8;
typedef __attribute__((ext_vector_type(4))) float f32x4;

__device__ __forceinline__ unsigned short f2bf(float f) {
    union { float f; unsigned u; } v; v.f = f;
    unsigned r = v.u + 0x7FFF + ((v.u >> 16) & 1);   // RNE
    return (unsigned short)(r >> 16);
}
__device__ __forceinline__ float bflo(unsigned u) {
    union { unsigned u; float f; } v; v.u = u << 16; return v.f;
}
__device__ __forceinline__ float bfhi(unsigned u) {
    union { unsigned u; float f; } v; v.u = u & 0xffff0000u; return v.f;
}

// ---------------- zero coarse-bucket counters ----------------
__global__ void k_init0(int* __restrict__ bcnt) {
    int i = blockIdx.x * 256 + threadIdx.x;
    if (i < NCB) bcnt[i] = 0;
}

// ---------------- coarse histogram: 196 buckets of 512 nodes ----------------
__global__ __launch_bounds__(1024) void k_hist(const int* __restrict__ dst, int* __restrict__ bcnt) {
    __shared__ int h[NCB];
    int t = threadIdx.x;
    if (t < NCB) h[t] = 0;
    __syncthreads();
    int base = blockIdx.x * CHK;
#pragma unroll
    for (int i = 0; i < 8; i++) {
        int e = base + i * 1024 + t;
        if (e < NE) atomicAdd(&h[dst[e] >> CBSH], 1);
    }
    __syncthreads();
    if (t < NCB && h[t]) atomicAdd(&bcnt[t], h[t]);
}

// ---------------- scan bucket counts -> ebase; zero gfill/pooled ----------------
__global__ __launch_bounds__(1024) void k_bscan(const int* __restrict__ bcnt, int* __restrict__ ebase,
                        int* __restrict__ gfill, float* __restrict__ pooled) {
    __shared__ int s[256];
    int t = threadIdx.x;
    if (t < 256) s[t] = (t < NCB) ? bcnt[t] : 0;
    __syncthreads();
    for (int off = 1; off < 256; off <<= 1) {
        int v = 0;
        if (t < 256 && t >= off) v = s[t - off];
        __syncthreads();
        if (t < 256) s[t] += v;
        __syncthreads();
    }
    if (t == 0) ebase[0] = 0;
    if (t < NCB) { ebase[t + 1] = s[t]; gfill[t] = 0; }
    for (int i = t; i < NG * CH; i += 1024) pooled[i] = 0.f;
}

// ---------------- pass A: counting-sort edges into coarse buckets ----------------
__global__ __launch_bounds__(1024) void k_passA(const int* __restrict__ src, const int* __restrict__ dst,
                        const int* __restrict__ ebase, int* __restrict__ gfill,
                        unsigned* __restrict__ ebuf) {
    __shared__ unsigned lbuf[CHK];
    __shared__ int hcnt[NCB];
    __shared__ int hbase[256];   // inclusive scan of hcnt
    __shared__ int goff[NCB];
    int t = threadIdx.x;
    if (t < NCB) hcnt[t] = 0;
    __syncthreads();
    int base = blockIdx.x * CHK;
    int cb[8], slot[8]; unsigned pk[8];
#pragma unroll
    for (int i = 0; i < 8; i++) {
        int e = base + i * 1024 + t;
        cb[i] = -1;
        if (e < NE) {
            int d = dst[e], s = src[e];
            cb[i] = d >> CBSH;
            pk[i] = ((unsigned)s << CBSH) | (unsigned)(d & 511);
            slot[i] = atomicAdd(&hcnt[cb[i]], 1);
        }
    }
    __syncthreads();
    if (t < 256) hbase[t] = (t < NCB) ? hcnt[t] : 0;
    __syncthreads();
    for (int off = 1; off < 256; off <<= 1) {
        int v = 0;
        if (t < 256 && t >= off) v = hbase[t - off];
        __syncthreads();
        if (t < 256) hbase[t] += v;
        __syncthreads();
    }
    if (t < NCB) {
        int c = hcnt[t];
        int g = c ? atomicAdd(&gfill[t], c) : 0;
        goff[t] = ebase[t] + g - (hbase[t] - c);
    }
    __syncthreads();
#pragma unroll
    for (int i = 0; i < 8; i++) {
        if (cb[i] >= 0) lbuf[hbase[cb[i]] - hcnt[cb[i]] + slot[i]] = pk[i];
    }
    __syncthreads();
    int total = min(NE - base, CHK);
    for (int p = t; p < total; p += 1024) {
        unsigned v = lbuf[p];
        int lo = 0, hi = NCB - 1;
        while (lo < hi) { int mid = (lo + hi) >> 1; if (hbase[mid] > p) hi = mid; else lo = mid + 1; }
        ebuf[goff[lo] + p] = v;
    }
}

// ---------------- pass B: per-bucket node sort -> csr/degi/rowst/dis ----------------
__global__ __launch_bounds__(1024) void k_passB(const unsigned* __restrict__ ebuf, const int* __restrict__ ebase,
                        int* __restrict__ degi, int* __restrict__ rowst,
                        float* __restrict__ dis, int* __restrict__ csr) {
    __shared__ int cnt[512];
    __shared__ int nbase[512];
    __shared__ int fill[512];
    __shared__ int stage[MAXB];
    int t = threadIdx.x;
    int cb = blockIdx.x;
    int nb0 = cb << CBSH;
    int ncnt = min(512, NN - nb0);
    int e0 = ebase[cb], e1 = ebase[cb + 1];
    if (t < 512) { cnt[t] = 0; fill[t] = 0; }
    __syncthreads();
    for (int e = e0 + t; e < e1; e += 1024)
        atomicAdd(&cnt[ebuf[e] & 511], 1);
    __syncthreads();
    if (t < 512) nbase[t] = cnt[t];
    __syncthreads();
    for (int off = 1; off < 512; off <<= 1) {
        int v = 0;
        if (t < 512 && t >= off) v = nbase[t - off];
        __syncthreads();
        if (t < 512) nbase[t] += v;
        __syncthreads();
    }
    for (int e = e0 + t; e < e1; e += 1024) {
        unsigned v = ebuf[e];
        int local = v & 511;
        int s = atomicAdd(&fill[local], 1);
        stage[nbase[local] - cnt[local] + s] = (int)(v >> CBSH);
    }
    __syncthreads();
    int total = e1 - e0;
    for (int p = t; p < total; p += 1024) csr[e0 + p] = stage[p];
    if (t < ncnt) {
        int c = cnt[t];
        degi[nb0 + t] = c;
        rowst[nb0 + t] = e0 + nbase[t] - c;
        dis[nb0 + t] = rsqrtf((float)c + 1.0f);
    }
}

// ---------------- graph start offsets from sorted batch ----------------
__global__ void k_gptr(const int* __restrict__ batch, int* __restrict__ gptr) {
    int n = blockIdx.x * 256 + threadIdx.x;
    if (n >= NN) return;
    int b = batch[n];
    int prev = (n == 0) ? -1 : batch[n - 1];
    for (int g = prev + 1; g <= b; g++) gptr[g] = n;
    if (n == NN - 1) {
        for (int g = b + 1; g <= NG; g++) gptr[g] = NN;
    }
}

// ---------------- both W [K][N] fp32 -> WT [N][K] bf16 ----------------
__global__ void k_castW(const float* __restrict__ W1, const float* __restrict__ W2,
                        unsigned short* __restrict__ wt1, unsigned short* __restrict__ wt2) {
    int i = blockIdx.x * 256 + threadIdx.x;
    if (i < CH * CH) {
        int k = i >> 7, n = i & 127;
        wt1[n * CH + k] = f2bf(W1[i]);
    } else if (i < 2 * CH * CH) {
        int j = i - CH * CH;
        int k = j >> 7, n = j & 127;
        wt2[n * CH + k] = f2bf(W2[j]);
    }
}

// ---------------- MFMA GEMM: out[row] = bf16( (A[row] @ W) * dis[row] ) ----------------
// Block 256 = 4 waves, 128 rows/block. Each wave: 32 rows (2 rowsets of 16) x 128 cols.
// B-fragments shared across the 2 rowsets -> B-load:MFMA = 1:2.
// F32IN: A is fp32 (layer 1, fuses the cast); else A is bf16.
template<bool F32IN>
__launch_bounds__(256, 2)
__global__ void k_gemm(const void* __restrict__ Av,
                       const unsigned short* __restrict__ WT,
                       const float* __restrict__ dis,
                       unsigned short* __restrict__ out) {
    int tid = threadIdx.x;
    int wave = tid >> 6, lane = tid & 63;
    int quad = lane >> 4, l16 = lane & 15;

    int rbase = blockIdx.x * 128 + wave * 32;

    bf16x8 af[2][4];
#pragma unroll
    for (int s = 0; s < 2; s++) {
        int row = rbase + s * 16 + l16;
        if (row >= NN) row = NN - 1;
        if (F32IN) {
            const float* arow = (const float*)Av + (size_t)row * CH + quad * 8;
#pragma unroll
            for (int ks = 0; ks < 4; ks++) {
                float4 lo = *(const float4*)(arow + ks * 32);
                float4 hi = *(const float4*)(arow + ks * 32 + 4);
                union { bf16x8 v; unsigned short u[8]; } tmp;
                tmp.u[0] = f2bf(lo.x); tmp.u[1] = f2bf(lo.y);
                tmp.u[2] = f2bf(lo.z); tmp.u[3] = f2bf(lo.w);
                tmp.u[4] = f2bf(hi.x); tmp.u[5] = f2bf(hi.y);
                tmp.u[6] = f2bf(hi.z); tmp.u[7] = f2bf(hi.w);
                af[s][ks] = tmp.v;
            }
        } else {
            const unsigned short* arow = (const unsigned short*)Av + (size_t)row * CH + quad * 8;
#pragma unroll
            for (int ks = 0; ks < 4; ks++) af[s][ks] = *(const bf16x8*)(arow + ks * 32);
        }
    }

    f32x4 acc[2][8];
#pragma unroll
    for (int s = 0; s < 2; s++)
#pragma unroll
        for (int t = 0; t < 8; t++) acc[s][t] = (f32x4){0.f, 0.f, 0.f, 0.f};

#pragma unroll
    for (int t = 0; t < 8; t++) {
        const unsigned short* wcol = WT + (size_t)(t * 16 + l16) * CH + quad * 8;
        bf16x8 b0 = *(const bf16x8*)(wcol);
        bf16x8 b1 = *(const bf16x8*)(wcol + 32);
        bf16x8 b2 = *(const bf16x8*)(wcol + 64);
        bf16x8 b3 = *(const bf16x8*)(wcol + 96);
#pragma unroll
        for (int s = 0; s < 2; s++) {
            acc[s][t] = __builtin_amdgcn_mfma_f32_16x16x32_bf16(af[s][0], b0, acc[s][t], 0, 0, 0);
            acc[s][t] = __builtin_amdgcn_mfma_f32_16x16x32_bf16(af[s][1], b1, acc[s][t], 0, 0, 0);
            acc[s][t] = __builtin_amdgcn_mfma_f32_16x16x32_bf16(af[s][2], b2, acc[s][t], 0, 0, 0);
            acc[s][t] = __builtin_amdgcn_mfma_f32_16x16x32_bf16(af[s][3], b3, acc[s][t], 0, 0, 0);
        }
    }

    // D layout per 16x16 tile: row = quad*4 + r, col = l16
#pragma unroll
    for (int s = 0; s < 2; s++) {
#pragma unroll
        for (int r = 0; r < 4; r++) {
            int orow = rbase + s * 16 + quad * 4 + r;
            if (orow < NN) {
                float d = dis[orow];
#pragma unroll
                for (int t = 0; t < 8; t++) {
                    out[(size_t)orow * CH + t * 16 + l16] = f2bf(acc[s][t][r] * d);
                }
            }
        }
    }
}

// ---------------- aggregation: out = bf16(relu(dis*(gather+self) + b)) ----------------
// one wave per node; 8 gathers in flight; scalarized csr indices
__global__ void k_agg(const unsigned short* __restrict__ ht, const int* __restrict__ rowst,
                      const int* __restrict__ degi, const int* __restrict__ csr,
                      const float* __restrict__ dis, const float* __restrict__ bias,
                      unsigned short* __restrict__ out) {
    int wave = threadIdx.x >> 6;
    int lane = threadIdx.x & 63;
    int n = blockIdx.x * 4 + wave;
    if (n >= NN) return;
    const unsigned* base = (const unsigned*)ht;
    unsigned sv = base[(size_t)n * 64 + lane];
    float a0[8], a1[8];
    a0[0] = bflo(sv); a1[0] = bfhi(sv);
#pragma unroll
    for (int u = 1; u < 8; u++) { a0[u] = 0.f; a1[u] = 0.f; }
    int start = __builtin_amdgcn_readfirstlane(rowst[n]);
    int c = __builtin_amdgcn_readfirstlane(degi[n]);
    int j = 0;
    for (; j + 7 < c; j += 8) {
        int idx[8];
#pragma unroll
        for (int u = 0; u < 8; u++) idx[u] = csr[start + j + u];
        unsigned v[8];
#pragma unroll
        for (int u = 0; u < 8; u++) v[u] = base[(size_t)idx[u] * 64 + lane];
#pragma unroll
        for (int u = 0; u < 8; u++) { a0[u] += bflo(v[u]); a1[u] += bfhi(v[u]); }
    }
    for (; j < c; j++) {
        unsigned v0 = base[(size_t)csr[start + j] * 64 + lane];
        a0[j & 7] += bflo(v0); a1[j & 7] += bfhi(v0);
    }
#pragma unroll
    for (int off = 4; off >= 1; off >>= 1)
#pragma unroll
        for (int u = 0; u < off; u++) { a0[u] += a0[u + off]; a1[u] += a1[u + off]; }
    float d = dis[n];
    float bb0 = bias[lane * 2], bb1 = bias[lane * 2 + 1];
    float ox = fmaxf(fmaf(d, a0[0], bb0), 0.f);
    float oy = fmaxf(fmaf(d, a1[0], bb1), 0.f);
    unsigned pk = ((unsigned)f2bf(oy) << 16) | (unsigned)f2bf(ox);
    ((unsigned*)out)[(size_t)n * 64 + lane] = pk;
}

// ---------------- mean pool: 8 splits/graph, LDS reduce, few atomics ----------------
__global__ __launch_bounds__(512) void k_pool2(const unsigned short* __restrict__ h,
                                               const int* __restrict__ gptr,
                                               float* __restrict__ pooled) {
    int g = blockIdx.x >> 3;       // graph
    int s = blockIdx.x & 7;        // split
    int gs = gptr[g], ge = gptr[g + 1];
    int len = ge - gs;
    int i0 = gs + (int)(((long long)len * s) >> 3);
    int i1 = gs + (int)(((long long)len * (s + 1)) >> 3);
    int t = threadIdx.x;
    int pr = t & 63;               // channel pair 0..63
    int ro = t >> 6;               // row group 0..7
    const unsigned* base = (const unsigned*)h;
    float s0 = 0.f, s1 = 0.f;
    for (int n = i0 + ro; n < i1; n += 8) {
        unsigned v = base[(size_t)n * 64 + pr];
        s0 += bflo(v); s1 += bfhi(v);
    }
    __shared__ float red[2][8][64];
    red[0][ro][pr] = s0; red[1][ro][pr] = s1;
    __syncthreads();
    for (int off = 4; off >= 1; off >>= 1) {
        if (ro < off) {
            red[0][ro][pr] += red[0][ro + off][pr];
            red[1][ro][pr] += red[1][ro + off][pr];
        }
        __syncthreads();
    }
    if (ro == 0) {
        atomicAdd(&pooled[g * CH + pr * 2],     red[0][0][pr]);
        atomicAdd(&pooled[g * CH + pr * 2 + 1], red[1][0][pr]);
    }
}

// ---------------- final FC: out = (pooled/cnt) @ Wfc + bfc ----------------
__global__ void k_final(const float* __restrict__ pooled, const int* __restrict__ gptr,
                        const float* __restrict__ Wfc, const float* __restrict__ bfc,
                        float* __restrict__ out) {
    int idx = blockIdx.x * 256 + threadIdx.x;
    if (idx >= NG * OUTC) return;
    int g = idx >> 4, o = idx & 15;
    float c = (float)(gptr[g + 1] - gptr[g]);
    float inv = 1.0f / fmaxf(c, 1.0f);
    float s = 0.f;
    for (int k = 0; k < CH; k++) s += pooled[g * CH + k] * Wfc[k * OUTC + o];
    out[idx] = fmaf(s, inv, bfc[o]);
}

extern "C" void kernel_launch(void* const* d_in, const int* in_sizes, int n_in,
                              void* d_out, int out_size, void* d_ws, size_t ws_size,
                              hipStream_t stream) {
    (void)in_sizes; (void)n_in; (void)out_size; (void)ws_size;
    const float* x   = (const float*)d_in[0];
    const float* W1  = (const float*)d_in[1];
    const float* b1  = (const float*)d_in[2];
    const float* W2  = (const float*)d_in[3];
    const float* b2  = (const float*)d_in[4];
    const float* Wfc = (const float*)d_in[5];
    const float* bfc = (const float*)d_in[6];
    const int* ei    = (const int*)d_in[7];
    const int* batch = (const int*)d_in[8];
    const int* esrc = ei;
    const int* edst = ei + NE;
    float* out = (float*)d_out;

    char* w = (char*)d_ws;
    unsigned short* bufA = (unsigned short*)w; w += (size_t)NN * CH * 2;
    unsigned short* bufB = (unsigned short*)w; w += (size_t)NN * CH * 2;
    unsigned short* wt1  = (unsigned short*)w; w += (size_t)CH * CH * 2;
    unsigned short* wt2  = (unsigned short*)w; w += (size_t)CH * CH * 2;
    unsigned* ebuf = (unsigned*)w; w += (size_t)NE * 4;
    int* csr    = (int*)w;    w += (size_t)NE * 4;
    int* degi   = (int*)w;    w += (size_t)NN * 4;
    int* rowst  = (int*)w;    w += (size_t)NN * 4;
    float* dis  = (float*)w;  w += (size_t)NN * 4;
    int* bcnt   = (int*)w;    w += NCB * 4;
    int* ebase  = (int*)w;    w += (NCB + 1) * 4;
    int* gfill  = (int*)w;    w += NCB * 4;
    int* gptr   = (int*)w;    w += (NG + 1) * 4;
    float* pooled = (float*)w; w += (size_t)NG * CH * 4;

    const int histBlocks = (NE + CHK - 1) / CHK;   // 196
    const int gemmBlocks = (NN + 127) / 128;       // 782

    k_init0<<<1, 256, 0, stream>>>(bcnt);
    k_hist<<<histBlocks, 1024, 0, stream>>>(edst, bcnt);
    k_bscan<<<1, 1024, 0, stream>>>(bcnt, ebase, gfill, pooled);
    k_passA<<<histBlocks, 1024, 0, stream>>>(esrc, edst, ebase, gfill, ebuf);
    k_passB<<<NCB, 1024, 0, stream>>>(ebuf, ebase, degi, rowst, dis, csr);
    k_gptr<<<(NN + 255) / 256, 256, 0, stream>>>(batch, gptr);

    k_castW<<<(2 * CH * CH + 255) / 256, 256, 0, stream>>>(W1, W2, wt1, wt2);

    // layer 1 (fp32 input, fused cast)
    k_gemm<true><<<gemmBlocks, 256, 0, stream>>>(x, wt1, dis, bufA);
    k_agg<<<NN / 4, 256, 0, stream>>>(bufA, rowst, degi, csr, dis, b1, bufB);
    // layer 2 (bf16 input)
    k_gemm<false><<<gemmBlocks, 256, 0, stream>>>(bufB, wt2, dis, bufA);
    k_agg<<<NN / 4, 256, 0, stream>>>(bufA, rowst, degi, csr, dis, b2, bufB);

    k_pool2<<<NG * PS, 512, 0, stream>>>(bufB, gptr, pooled);
    k_final<<<(NG * OUTC + 255) / 256, 256, 0, stream>>>(pooled, gptr, Wfc, bfc, out);
}

// Round 6
// 328.000 us; speedup vs baseline: 2.1736x; 1.0184x over previous
//
#include <hip/hip_runtime.h>
#include <math.h>

#define NN 100000
#define NE 1600000
#define CH 128
#define OUTC 16
#define NG 64

#define CBSH 9                      // 512 nodes per coarse bucket
#define NCB 196                     // ceil(NN / 512)
#define CHK 8192                    // edges per passA block
#define MAXB 12288                  // csr staging capacity per bucket (avg 8192)
#define PS 8                        // pool splits per graph

typedef __attribute__((ext_vector_type(8))) short bf16x8;
typedef __attribute__((ext_vector_type(4))) float f32x4;

__device__ __forceinline__ unsigned short f2bf(float f) {
    union { float f; unsigned u; } v; v.f = f;
    unsigned r = v.u + 0x7FFF + ((v.u >> 16) & 1);   // RNE
    return (unsigned short)(r >> 16);
}
__device__ __forceinline__ float bflo(unsigned u) {
    union { unsigned u; float f; } v; v.u = u << 16; return v.f;
}
__device__ __forceinline__ float bfhi(unsigned u) {
    union { unsigned u; float f; } v; v.u = u & 0xffff0000u; return v.f;
}

// ---------------- prep: cast W1/W2 -> WT bf16, zero bcnt, build gptr ----------------
__global__ void k_prep(const float* __restrict__ W1, const float* __restrict__ W2,
                       unsigned short* __restrict__ wt1, unsigned short* __restrict__ wt2,
                       const int* __restrict__ batch, int* __restrict__ gptr,
                       int* __restrict__ bcnt) {
    int i = blockIdx.x * 256 + threadIdx.x;
    if (i < CH * CH) {
        int k = i >> 7, n = i & 127;
        wt1[n * CH + k] = f2bf(W1[i]);
    } else if (i < 2 * CH * CH) {
        int j = i - CH * CH;
        int k = j >> 7, n = j & 127;
        wt2[n * CH + k] = f2bf(W2[j]);
    }
    if (i < NCB) bcnt[i] = 0;
    if (i < NN) {
        int b = batch[i];
        int prev = (i == 0) ? -1 : batch[i - 1];
        for (int g = prev + 1; g <= b; g++) gptr[g] = i;
        if (i == NN - 1) {
            for (int g = b + 1; g <= NG; g++) gptr[g] = NN;
        }
    }
}

// ---------------- coarse histogram: 196 buckets of 512 nodes ----------------
__global__ __launch_bounds__(1024) void k_hist(const int* __restrict__ dst, int* __restrict__ bcnt) {
    __shared__ int h[NCB];
    int t = threadIdx.x;
    if (t < NCB) h[t] = 0;
    __syncthreads();
    int base = blockIdx.x * CHK;
#pragma unroll
    for (int i = 0; i < 8; i++) {
        int e = base + i * 1024 + t;
        if (e < NE) atomicAdd(&h[dst[e] >> CBSH], 1);
    }
    __syncthreads();
    if (t < NCB && h[t]) atomicAdd(&bcnt[t], h[t]);
}

// ---------------- scan bucket counts -> ebase; zero gfill/pooled ----------------
__global__ __launch_bounds__(1024) void k_bscan(const int* __restrict__ bcnt, int* __restrict__ ebase,
                        int* __restrict__ gfill, float* __restrict__ pooled) {
    __shared__ int s[256];
    int t = threadIdx.x;
    if (t < 256) s[t] = (t < NCB) ? bcnt[t] : 0;
    __syncthreads();
    for (int off = 1; off < 256; off <<= 1) {
        int v = 0;
        if (t < 256 && t >= off) v = s[t - off];
        __syncthreads();
        if (t < 256) s[t] += v;
        __syncthreads();
    }
    if (t == 0) ebase[0] = 0;
    if (t < NCB) { ebase[t + 1] = s[t]; gfill[t] = 0; }
    for (int i = t; i < NG * CH; i += 1024) pooled[i] = 0.f;
}

// ---------------- pass A: counting-sort edges into coarse buckets ----------------
// lbyte[pos] records the bucket so copy-out avoids a binary search.
__global__ __launch_bounds__(1024) void k_passA(const int* __restrict__ src, const int* __restrict__ dst,
                        const int* __restrict__ ebase, int* __restrict__ gfill,
                        unsigned* __restrict__ ebuf) {
    __shared__ unsigned lbuf[CHK];
    __shared__ unsigned char lbyte[CHK];
    __shared__ int hcnt[NCB];
    __shared__ int hbase[256];   // inclusive scan of hcnt
    __shared__ int goff[NCB];
    int t = threadIdx.x;
    if (t < NCB) hcnt[t] = 0;
    __syncthreads();
    int base = blockIdx.x * CHK;
    int cb[8], slot[8]; unsigned pk[8];
#pragma unroll
    for (int i = 0; i < 8; i++) {
        int e = base + i * 1024 + t;
        cb[i] = -1;
        if (e < NE) {
            int d = dst[e], s = src[e];
            cb[i] = d >> CBSH;
            pk[i] = ((unsigned)s << CBSH) | (unsigned)(d & 511);
            slot[i] = atomicAdd(&hcnt[cb[i]], 1);
        }
    }
    __syncthreads();
    if (t < 256) hbase[t] = (t < NCB) ? hcnt[t] : 0;
    __syncthreads();
    for (int off = 1; off < 256; off <<= 1) {
        int v = 0;
        if (t < 256 && t >= off) v = hbase[t - off];
        __syncthreads();
        if (t < 256) hbase[t] += v;
        __syncthreads();
    }
    if (t < NCB) {
        int c = hcnt[t];
        int g = c ? atomicAdd(&gfill[t], c) : 0;
        goff[t] = ebase[t] + g - (hbase[t] - c);
    }
    __syncthreads();
#pragma unroll
    for (int i = 0; i < 8; i++) {
        if (cb[i] >= 0) {
            int pos = hbase[cb[i]] - hcnt[cb[i]] + slot[i];
            lbuf[pos] = pk[i];
            lbyte[pos] = (unsigned char)cb[i];
        }
    }
    __syncthreads();
    int total = min(NE - base, CHK);
    for (int p = t; p < total; p += 1024) {
        unsigned v = lbuf[p];
        int b = lbyte[p];
        ebuf[goff[b] + p] = v;
    }
}

// ---------------- pass B: per-bucket node sort -> csr/degi/rowst/dis ----------------
__global__ __launch_bounds__(1024) void k_passB(const unsigned* __restrict__ ebuf, const int* __restrict__ ebase,
                        int* __restrict__ degi, int* __restrict__ rowst,
                        float* __restrict__ dis, int* __restrict__ csr) {
    __shared__ int cnt[512];
    __shared__ int nbase[512];
    __shared__ int fill[512];
    __shared__ int stage[MAXB];
    int t = threadIdx.x;
    int cb = blockIdx.x;
    int nb0 = cb << CBSH;
    int ncnt = min(512, NN - nb0);
    int e0 = ebase[cb], e1 = ebase[cb + 1];
    if (t < 512) { cnt[t] = 0; fill[t] = 0; }
    __syncthreads();
    for (int e = e0 + t; e < e1; e += 1024)
        atomicAdd(&cnt[ebuf[e] & 511], 1);
    __syncthreads();
    if (t < 512) nbase[t] = cnt[t];
    __syncthreads();
    for (int off = 1; off < 512; off <<= 1) {
        int v = 0;
        if (t < 512 && t >= off) v = nbase[t - off];
        __syncthreads();
        if (t < 512) nbase[t] += v;
        __syncthreads();
    }
    for (int e = e0 + t; e < e1; e += 1024) {
        unsigned v = ebuf[e];
        int local = v & 511;
        int s = atomicAdd(&fill[local], 1);
        stage[nbase[local] - cnt[local] + s] = (int)(v >> CBSH);
    }
    __syncthreads();
    int total = e1 - e0;
    for (int p = t; p < total; p += 1024) csr[e0 + p] = stage[p];
    if (t < ncnt) {
        int c = cnt[t];
        degi[nb0 + t] = c;
        rowst[nb0 + t] = e0 + nbase[t] - c;
        dis[nb0 + t] = rsqrtf((float)c + 1.0f);
    }
}

// ---------------- MFMA GEMM: out[row] = bf16( (A[row] @ W) * dis[row] ) ----------------
// Block 256 = 4 waves, 128 rows/block. Each wave: 32 rows (2 rowsets of 16) x 128 cols.
// F32IN: A is fp32 (layer 1, fuses the cast); else A is bf16.
template<bool F32IN>
__launch_bounds__(256, 2)
__global__ void k_gemm(const void* __restrict__ Av,
                       const unsigned short* __restrict__ WT,
                       const float* __restrict__ dis,
                       unsigned short* __restrict__ out) {
    int tid = threadIdx.x;
    int wave = tid >> 6, lane = tid & 63;
    int quad = lane >> 4, l16 = lane & 15;

    int rbase = blockIdx.x * 128 + wave * 32;

    bf16x8 af[2][4];
#pragma unroll
    for (int s = 0; s < 2; s++) {
        int row = rbase + s * 16 + l16;
        if (row >= NN) row = NN - 1;
        if (F32IN) {
            const float* arow = (const float*)Av + (size_t)row * CH + quad * 8;
#pragma unroll
            for (int ks = 0; ks < 4; ks++) {
                float4 lo = *(const float4*)(arow + ks * 32);
                float4 hi = *(const float4*)(arow + ks * 32 + 4);
                union { bf16x8 v; unsigned short u[8]; } tmp;
                tmp.u[0] = f2bf(lo.x); tmp.u[1] = f2bf(lo.y);
                tmp.u[2] = f2bf(lo.z); tmp.u[3] = f2bf(lo.w);
                tmp.u[4] = f2bf(hi.x); tmp.u[5] = f2bf(hi.y);
                tmp.u[6] = f2bf(hi.z); tmp.u[7] = f2bf(hi.w);
                af[s][ks] = tmp.v;
            }
        } else {
            const unsigned short* arow = (const unsigned short*)Av + (size_t)row * CH + quad * 8;
#pragma unroll
            for (int ks = 0; ks < 4; ks++) af[s][ks] = *(const bf16x8*)(arow + ks * 32);
        }
    }

    f32x4 acc[2][8];
#pragma unroll
    for (int s = 0; s < 2; s++)
#pragma unroll
        for (int t = 0; t < 8; t++) acc[s][t] = (f32x4){0.f, 0.f, 0.f, 0.f};

#pragma unroll
    for (int t = 0; t < 8; t++) {
        const unsigned short* wcol = WT + (size_t)(t * 16 + l16) * CH + quad * 8;
        bf16x8 b0 = *(const bf16x8*)(wcol);
        bf16x8 b1 = *(const bf16x8*)(wcol + 32);
        bf16x8 b2 = *(const bf16x8*)(wcol + 64);
        bf16x8 b3 = *(const bf16x8*)(wcol + 96);
#pragma unroll
        for (int s = 0; s < 2; s++) {
            acc[s][t] = __builtin_amdgcn_mfma_f32_16x16x32_bf16(af[s][0], b0, acc[s][t], 0, 0, 0);
            acc[s][t] = __builtin_amdgcn_mfma_f32_16x16x32_bf16(af[s][1], b1, acc[s][t], 0, 0, 0);
            acc[s][t] = __builtin_amdgcn_mfma_f32_16x16x32_bf16(af[s][2], b2, acc[s][t], 0, 0, 0);
            acc[s][t] = __builtin_amdgcn_mfma_f32_16x16x32_bf16(af[s][3], b3, acc[s][t], 0, 0, 0);
        }
    }

    // D layout per 16x16 tile: row = quad*4 + r, col = l16
#pragma unroll
    for (int s = 0; s < 2; s++) {
#pragma unroll
        for (int r = 0; r < 4; r++) {
            int orow = rbase + s * 16 + quad * 4 + r;
            if (orow < NN) {
                float d = dis[orow];
#pragma unroll
                for (int t = 0; t < 8; t++) {
                    out[(size_t)orow * CH + t * 16 + l16] = f2bf(acc[s][t][r] * d);
                }
            }
        }
    }
}

// ---------------- aggregation: out = bf16(relu(dis*(gather+self) + b)) ----------------
// one wave per node; 8 gathers in flight; fully scalar index/address chain
__global__ void k_agg(const unsigned short* __restrict__ ht, const int* __restrict__ rowst,
                      const int* __restrict__ degi, const int* __restrict__ csr,
                      const float* __restrict__ dis, const float* __restrict__ bias,
                      unsigned short* __restrict__ out) {
    int wave = threadIdx.x >> 6;
    int lane = threadIdx.x & 63;
    int n = blockIdx.x * 4 + wave;
    if (n >= NN) return;
    const unsigned* base = (const unsigned*)ht;
    unsigned sv = base[(size_t)n * 64 + lane];
    float a0[8], a1[8];
    a0[0] = bflo(sv); a1[0] = bfhi(sv);
#pragma unroll
    for (int u = 1; u < 8; u++) { a0[u] = 0.f; a1[u] = 0.f; }
    int start = __builtin_amdgcn_readfirstlane(rowst[n]);
    int c = __builtin_amdgcn_readfirstlane(degi[n]);
    int j = 0;
    for (; j + 7 < c; j += 8) {
        unsigned v[8];
#pragma unroll
        for (int u = 0; u < 8; u++) {
            int si = __builtin_amdgcn_readfirstlane(csr[start + j + u]);
            v[u] = base[(size_t)si * 64 + lane];
        }
#pragma unroll
        for (int u = 0; u < 8; u++) { a0[u] += bflo(v[u]); a1[u] += bfhi(v[u]); }
    }
    for (; j < c; j++) {
        int si = __builtin_amdgcn_readfirstlane(csr[start + j]);
        unsigned v0 = base[(size_t)si * 64 + lane];
        a0[j & 7] += bflo(v0); a1[j & 7] += bfhi(v0);
    }
#pragma unroll
    for (int off = 4; off >= 1; off >>= 1)
#pragma unroll
        for (int u = 0; u < off; u++) { a0[u] += a0[u + off]; a1[u] += a1[u + off]; }
    float d = dis[n];
    float bb0 = bias[lane * 2], bb1 = bias[lane * 2 + 1];
    float ox = fmaxf(fmaf(d, a0[0], bb0), 0.f);
    float oy = fmaxf(fmaf(d, a1[0], bb1), 0.f);
    unsigned pk = ((unsigned)f2bf(oy) << 16) | (unsigned)f2bf(ox);
    ((unsigned*)out)[(size_t)n * 64 + lane] = pk;
}

// ---------------- mean pool: 8 splits/graph, LDS reduce, few atomics ----------------
__global__ __launch_bounds__(512) void k_pool2(const unsigned short* __restrict__ h,
                                               const int* __restrict__ gptr,
                                               float* __restrict__ pooled) {
    int g = blockIdx.x >> 3;       // graph
    int s = blockIdx.x & 7;        // split
    int gs = gptr[g], ge = gptr[g + 1];
    int len = ge - gs;
    int i0 = gs + (int)(((long long)len * s) >> 3);
    int i1 = gs + (int)(((long long)len * (s + 1)) >> 3);
    int t = threadIdx.x;
    int pr = t & 63;               // channel pair 0..63
    int ro = t >> 6;               // row group 0..7
    const unsigned* base = (const unsigned*)h;
    float s0 = 0.f, s1 = 0.f;
    for (int n = i0 + ro; n < i1; n += 8) {
        unsigned v = base[(size_t)n * 64 + pr];
        s0 += bflo(v); s1 += bfhi(v);
    }
    __shared__ float red[2][8][64];
    red[0][ro][pr] = s0; red[1][ro][pr] = s1;
    __syncthreads();
    for (int off = 4; off >= 1; off >>= 1) {
        if (ro < off) {
            red[0][ro][pr] += red[0][ro + off][pr];
            red[1][ro][pr] += red[1][ro + off][pr];
        }
        __syncthreads();
    }
    if (ro == 0) {
        atomicAdd(&pooled[g * CH + pr * 2],     red[0][0][pr]);
        atomicAdd(&pooled[g * CH + pr * 2 + 1], red[1][0][pr]);
    }
}

// ---------------- final FC: out = (pooled/cnt) @ Wfc + bfc ----------------
__global__ void k_final(const float* __restrict__ pooled, const int* __restrict__ gptr,
                        const float* __restrict__ Wfc, const float* __restrict__ bfc,
                        float* __restrict__ out) {
    int idx = blockIdx.x * 256 + threadIdx.x;
    if (idx >= NG * OUTC) return;
    int g = idx >> 4, o = idx & 15;
    float c = (float)(gptr[g + 1] - gptr[g]);
    float inv = 1.0f / fmaxf(c, 1.0f);
    float s = 0.f;
    for (int k = 0; k < CH; k++) s += pooled[g * CH + k] * Wfc[k * OUTC + o];
    out[idx] = fmaf(s, inv, bfc[o]);
}

extern "C" void kernel_launch(void* const* d_in, const int* in_sizes, int n_in,
                              void* d_out, int out_size, void* d_ws, size_t ws_size,
                              hipStream_t stream) {
    (void)in_sizes; (void)n_in; (void)out_size; (void)ws_size;
    const float* x   = (const float*)d_in[0];
    const float* W1  = (const float*)d_in[1];
    const float* b1  = (const float*)d_in[2];
    const float* W2  = (const float*)d_in[3];
    const float* b2  = (const float*)d_in[4];
    const float* Wfc = (const float*)d_in[5];
    const float* bfc = (const float*)d_in[6];
    const int* ei    = (const int*)d_in[7];
    const int* batch = (const int*)d_in[8];
    const int* esrc = ei;
    const int* edst = ei + NE;
    float* out = (float*)d_out;

    char* w = (char*)d_ws;
    unsigned short* bufA = (unsigned short*)w; w += (size_t)NN * CH * 2;
    unsigned short* bufB = (unsigned short*)w; w += (size_t)NN * CH * 2;
    unsigned short* wt1  = (unsigned short*)w; w += (size_t)CH * CH * 2;
    unsigned short* wt2  = (unsigned short*)w; w += (size_t)CH * CH * 2;
    unsigned* ebuf = (unsigned*)w; w += (size_t)NE * 4;
    int* csr    = (int*)w;    w += (size_t)NE * 4;
    int* degi   = (int*)w;    w += (size_t)NN * 4;
    int* rowst  = (int*)w;    w += (size_t)NN * 4;
    float* dis  = (float*)w;  w += (size_t)NN * 4;
    int* bcnt   = (int*)w;    w += NCB * 4;
    int* ebase  = (int*)w;    w += (NCB + 1) * 4;
    int* gfill  = (int*)w;    w += NCB * 4;
    int* gptr   = (int*)w;    w += (NG + 1) * 4;
    float* pooled = (float*)w; w += (size_t)NG * CH * 4;

    const int histBlocks = (NE + CHK - 1) / CHK;   // 196
    const int gemmBlocks = (NN + 127) / 128;       // 782

    k_prep<<<(NN + 255) / 256, 256, 0, stream>>>(W1, W2, wt1, wt2, batch, gptr, bcnt);
    k_hist<<<histBlocks, 1024, 0, stream>>>(edst, bcnt);
    k_bscan<<<1, 1024, 0, stream>>>(bcnt, ebase, gfill, pooled);
    k_passA<<<histBlocks, 1024, 0, stream>>>(esrc, edst, ebase, gfill, ebuf);
    k_passB<<<NCB, 1024, 0, stream>>>(ebuf, ebase, degi, rowst, dis, csr);

    // layer 1 (fp32 input, fused cast)
    k_gemm<true><<<gemmBlocks, 256, 0, stream>>>(x, wt1, dis, bufA);
    k_agg<<<NN / 4, 256, 0, stream>>>(bufA, rowst, degi, csr, dis, b1, bufB);
    // layer 2 (bf16 input)
    k_gemm<false><<<gemmBlocks, 256, 0, stream>>>(bufB, wt2, dis, bufA);
    k_agg<<<NN / 4, 256, 0, stream>>>(bufA, rowst, degi, csr, dis, b2, bufB);

    k_pool2<<<NG * PS, 512, 0, stream>>>(bufB, gptr, pooled);
    k_final<<<(NG * OUTC + 255) / 256, 256, 0, stream>>>(pooled, gptr, Wfc, bfc, out);
}